// Round 13
// baseline (301.049 us; speedup 1.0000x reference)
//
#include <hip/hip_runtime.h>
#include <hip/hip_fp16.h>

#define N_NODES 50000
#define NFEAT   256
#define NGRAPH  64
#define NEDGE   800000
#define NBLK_SCAN 196  // ceil(50000/256)

typedef __attribute__((ext_vector_type(8))) _Float16 half8;
typedef __attribute__((ext_vector_type(2))) _Float16 h2v;
typedef __attribute__((ext_vector_type(4))) float f32x4;
struct alignas(8) US4 { unsigned short x, y, z, w; };

static __device__ __forceinline__ float h2f(unsigned short u) {
    return __half2float(__ushort_as_half(u));
}
static __device__ __forceinline__ unsigned short f2h(float f) {
    return __half_as_ushort(__float2half(f));
}

// ================= CSR build =================
// count + per-edge rank (old value of the counter) in one pass
__global__ void k_count(const int* __restrict__ dst, int* __restrict__ cnt,
                        int* __restrict__ rank) {
    int e = blockIdx.x * 256 + threadIdx.x;
    if (e < NEDGE) rank[e] = atomicAdd(&cnt[dst[e]], 1);
}

__global__ __launch_bounds__(256) void k_scan1(const int* __restrict__ cnt,
                                               int* __restrict__ row_start,
                                               int* __restrict__ bsum) {
    const int t = threadIdx.x, i = blockIdx.x * 256 + t;
    const int lane = t & 63, w = t >> 6;
    const int c = (i < N_NODES) ? cnt[i] : 0;
    int incl = c;
#pragma unroll
    for (int off = 1; off < 64; off <<= 1) {
        int u = __shfl_up(incl, off, 64);
        if (lane >= off) incl += u;
    }
    __shared__ int wtot[4];
    if (lane == 63) wtot[w] = incl;
    __syncthreads();
    int wbase = 0;
#pragma unroll
    for (int k = 0; k < 4; ++k) wbase += (k < w) ? wtot[k] : 0;
    if (i < N_NODES) row_start[i] = wbase + incl - c;
    if (t == 255) bsum[blockIdx.x] = wbase + incl;
}

__global__ __launch_bounds__(256) void k_scan2(int* __restrict__ bsum) {
    const int t = threadIdx.x, lane = t & 63, w = t >> 6;
    const int c = (t < NBLK_SCAN) ? bsum[t] : 0;
    int incl = c;
#pragma unroll
    for (int off = 1; off < 64; off <<= 1) {
        int u = __shfl_up(incl, off, 64);
        if (lane >= off) incl += u;
    }
    __shared__ int wtot[4];
    if (lane == 63) wtot[w] = incl;
    __syncthreads();
    int wbase = 0;
#pragma unroll
    for (int k = 0; k < 4; ++k) wbase += (k < w) ? wtot[k] : 0;
    if (t < NBLK_SCAN) bsum[t] = wbase + incl - c;
}

__global__ void k_scan3(int* __restrict__ row_start, const int* __restrict__ bsum,
                        const int* __restrict__ cnt, float* __restrict__ dinv) {
    const int i = blockIdx.x * 256 + threadIdx.x;
    if (i >= N_NODES) return;
    row_start[i] += bsum[blockIdx.x];
    dinv[i] = rsqrtf((float)cnt[i] + 1.0f);
    if (i == 0) row_start[N_NODES] = NEDGE;
}

// atomic-free placement via precomputed rank
__global__ void k_place(const int* __restrict__ src, const int* __restrict__ dst,
                        const int* __restrict__ rank, const int* __restrict__ row_start,
                        const float* __restrict__ dinv, unsigned int* __restrict__ csr) {
    int e = blockIdx.x * 256 + threadIdx.x;
    if (e < NEDGE) {
        int s = src[e], d = dst[e];
        float norm = dinv[s] * dinv[d];
        csr[row_start[d] + rank[e]] =
            ((unsigned int)f2h(norm) << 16) | (unsigned int)s;
    }
}

// ================= W prep: W[k][n] f32 -> Wt [n][k] fp16 =================
__global__ void k_prep_w(const float* __restrict__ W1, const float* __restrict__ W2,
                         unsigned short* __restrict__ w1t, unsigned short* __restrict__ w2t) {
    const int l = blockIdx.x >> 8;
    const int idx = (blockIdx.x & 255) * 256 + threadIdx.x;
    const int n = idx >> 8, k = idx & 255;
    const float* W = l ? W2 : W1;
    unsigned short* wt = l ? w2t : w1t;
    wt[n * 256 + k] = f2h(W[k * 256 + n]);
}

// ================= x f32 -> fp16 [2][N][128] =================
__global__ void k_half_x(const float* __restrict__ x, unsigned short* __restrict__ hx) {
    const int idx = blockIdx.x * 256 + threadIdx.x;  // over N*32 half8-units
    if (idx >= N_NODES * 32) return;
    const int node = idx >> 5, sub = idx & 31;
    const int half = sub >> 4, fl = sub & 15;
    const float* ap = x + (size_t)node * 256 + half * 128 + fl * 8;
    const float4 p0 = *(const float4*)ap;
    const float4 p1 = *(const float4*)(ap + 4);
    half8 h;
    h[0] = (_Float16)p0.x; h[1] = (_Float16)p0.y;
    h[2] = (_Float16)p0.z; h[3] = (_Float16)p0.w;
    h[4] = (_Float16)p1.x; h[5] = (_Float16)p1.y;
    h[6] = (_Float16)p1.z; h[7] = (_Float16)p1.w;
    *(half8*)(hx + (size_t)half * N_NODES * 128 + (size_t)node * 128 + fl * 8) = h;
}

// ================= fp16 MFMA GEMM — weight-stationary in registers =================
// 512 thr = 8 waves; wave w owns W-cols [w*32, w*32+32) held in 64 VGPRs (bf[2][8]).
// NO LDS, NO barriers. Per 16-row chunk: 8 A-loads (ping-pong) + 16 MFMA + 2x8B stores.
// Swapped-operand MFMA: mfma(bf, af) -> lane holds (row=lr, 4 consecutive cols).
// All 8 waves read the same A rows -> L1/L2 dedup; each A row HBM-fetched once.
__global__ __launch_bounds__(512, 3) void k_gemm_ws(const unsigned short* __restrict__ Ah,
                                                    const unsigned short* __restrict__ Wt,
                                                    unsigned short* __restrict__ Ch, int M) {
    const int t = threadIdx.x;
    const int w = t >> 6, lane = t & 63;
    const int lr = lane & 15, g = lane >> 4;
    const int c0 = w * 32;
    const int m0 = blockIdx.x * 128;

    // one-time: W-strip into registers
    half8 bf[2][8];
#pragma unroll
    for (int ni = 0; ni < 2; ++ni)
#pragma unroll
        for (int ks = 0; ks < 8; ++ks)
            bf[ni][ks] = *(const half8*)&Wt[(size_t)(c0 + ni * 16 + lr) * 256 + ks * 32 + g * 8];

    half8 aA[8], aB[8];

#define LOADA(C, DST)                                                                     \
    {                                                                                     \
        const int row = min(m0 + (C) * 16 + lr, M - 1);                                   \
        _Pragma("unroll") for (int ks = 0; ks < 8; ++ks)                                  \
            DST[ks] = *(const half8*)(Ah + (size_t)(ks >> 2) * (size_t)N_NODES * 128 +    \
                                      (size_t)row * 128 + (ks & 3) * 32 + g * 8);         \
    }
#define COMPUTE(C, SRC)                                                                   \
    {                                                                                     \
        f32x4 acc0 = {}, acc1 = {};                                                       \
        _Pragma("unroll") for (int ks = 0; ks < 8; ++ks) {                                \
            acc0 = __builtin_amdgcn_mfma_f32_16x16x32_f16(bf[0][ks], SRC[ks], acc0, 0, 0, 0); \
            acc1 = __builtin_amdgcn_mfma_f32_16x16x32_f16(bf[1][ks], SRC[ks], acc1, 0, 0, 0); \
        }                                                                                 \
        const int row = m0 + (C) * 16 + lr;                                               \
        if (row < M) {                                                                    \
            US4 o0, o1;                                                                   \
            o0.x = f2h(acc0[0]); o0.y = f2h(acc0[1]);                                     \
            o0.z = f2h(acc0[2]); o0.w = f2h(acc0[3]);                                     \
            o1.x = f2h(acc1[0]); o1.y = f2h(acc1[1]);                                     \
            o1.z = f2h(acc1[2]); o1.w = f2h(acc1[3]);                                     \
            const int col0 = c0 + g * 4;                                                  \
            const int col1 = c0 + 16 + g * 4;                                             \
            *(US4*)(Ch + (size_t)(col0 >> 7) * (size_t)N_NODES * 128 +                    \
                    (size_t)row * 128 + (col0 & 127)) = o0;                               \
            *(US4*)(Ch + (size_t)(col1 >> 7) * (size_t)N_NODES * 128 +                    \
                    (size_t)row * 128 + (col1 & 127)) = o1;                               \
        }                                                                                 \
    }

    LOADA(0, aA)
    LOADA(1, aB)
    COMPUTE(0, aA)
    LOADA(2, aA)
    COMPUTE(1, aB)
    LOADA(3, aB)
    COMPUTE(2, aA)
    LOADA(4, aA)
    COMPUTE(3, aB)
    LOADA(5, aB)
    COMPUTE(4, aA)
    LOADA(6, aA)
    COMPUTE(5, aB)
    LOADA(7, aB)
    COMPUTE(6, aA)
    COMPUTE(7, aB)
#undef LOADA
#undef COMPUTE
}

// ================= aggregation: wave per (node, half); 16 lanes/edge; fdot2 ===========
__global__ __launch_bounds__(256) void k_aggregate(const unsigned short* __restrict__ h16,
                                                   const int* __restrict__ row_start,
                                                   const unsigned int* __restrict__ csr,
                                                   const float* __restrict__ dinv,
                                                   const float* __restrict__ bias,
                                                   unsigned short* __restrict__ out) {
    const int wid = blockIdx.x * 4 + (threadIdx.x >> 6);
    if (wid >= 2 * N_NODES) return;
    const int half = (wid >= N_NODES) ? 1 : 0;  // all half-0 wids first
    const int node = wid - half * N_NODES;
    const int lane = threadIdx.x & 63;
    const int sub = lane >> 4;   // 0..3: edge-pair index
    const int fl = lane & 15;    // 8 feats per lane
    const unsigned int* hu = (const unsigned int*)(h16 + (size_t)half * N_NODES * 128);

    float acc[8] = {};
    const int s0 = row_start[node], s1 = row_start[node + 1];
    const unsigned int* row = csr + s0;
    const int n = s1 - s0;

#define EDGEPAIR(EA, EB)                                                              \
    {                                                                                 \
        const unsigned int wnp = __builtin_amdgcn_perm(EB, EA, 0x07060302u);          \
        const h2v wn2 = __builtin_bit_cast(h2v, wnp);                                 \
        const uint4 va = *(const uint4*)(hu + (size_t)((EA)&0xffffu) * 64 + fl * 4);  \
        const uint4 vb = *(const uint4*)(hu + (size_t)((EB)&0xffffu) * 64 + fl * 4);  \
        unsigned int plo, phi;                                                        \
        plo = __builtin_amdgcn_perm(vb.x, va.x, 0x05040100u);                         \
        phi = __builtin_amdgcn_perm(vb.x, va.x, 0x07060302u);                         \
        acc[0] = __builtin_amdgcn_fdot2(__builtin_bit_cast(h2v, plo), wn2, acc[0], false); \
        acc[1] = __builtin_amdgcn_fdot2(__builtin_bit_cast(h2v, phi), wn2, acc[1], false); \
        plo = __builtin_amdgcn_perm(vb.y, va.y, 0x05040100u);                         \
        phi = __builtin_amdgcn_perm(vb.y, va.y, 0x07060302u);                         \
        acc[2] = __builtin_amdgcn_fdot2(__builtin_bit_cast(h2v, plo), wn2, acc[2], false); \
        acc[3] = __builtin_amdgcn_fdot2(__builtin_bit_cast(h2v, phi), wn2, acc[3], false); \
        plo = __builtin_amdgcn_perm(vb.z, va.z, 0x05040100u);                         \
        phi = __builtin_amdgcn_perm(vb.z, va.z, 0x07060302u);                         \
        acc[4] = __builtin_amdgcn_fdot2(__builtin_bit_cast(h2v, plo), wn2, acc[4], false); \
        acc[5] = __builtin_amdgcn_fdot2(__builtin_bit_cast(h2v, phi), wn2, acc[5], false); \
        plo = __builtin_amdgcn_perm(vb.w, va.w, 0x05040100u);                         \
        phi = __builtin_amdgcn_perm(vb.w, va.w, 0x07060302u);                         \
        acc[6] = __builtin_amdgcn_fdot2(__builtin_bit_cast(h2v, plo), wn2, acc[6], false); \
        acc[7] = __builtin_amdgcn_fdot2(__builtin_bit_cast(h2v, phi), wn2, acc[7], false); \
    }

    const int nfull = n & ~7;
    int j = 0;
    for (; j < nfull; j += 8) {
        const unsigned int ea = row[j + sub * 2];
        const unsigned int eb = row[j + sub * 2 + 1];
        EDGEPAIR(ea, eb)
    }
    if (j < n) {  // guarded tail (invalid slots: e=0 -> wn=0 -> contributes 0)
        const int ia = j + sub * 2, ib = ia + 1;
        const unsigned int ea = (ia < n) ? row[ia] : 0u;
        const unsigned int eb = (ib < n) ? row[ib] : 0u;
        EDGEPAIR(ea, eb)
    }
#undef EDGEPAIR

#pragma unroll
    for (int i = 0; i < 8; ++i) {
        acc[i] += __shfl_xor(acc[i], 16, 64);
        acc[i] += __shfl_xor(acc[i], 32, 64);
    }

    if (sub == 0) {  // lanes 0-15 hold the final sums
        const float dd = dinv[node];
        const float ws = dd * dd;
        const uint4 sh = *(const uint4*)(hu + (size_t)node * 64 + fl * 4);
        const float4 b0 = *(const float4*)(bias + half * 128 + fl * 8);
        const float4 b1 = *(const float4*)(bias + half * 128 + fl * 8 + 4);
        float r[8];
        r[0] = fmaf(h2f((unsigned short)(sh.x & 0xffff)), ws, acc[0]) + b0.x;
        r[1] = fmaf(h2f((unsigned short)(sh.x >> 16)),    ws, acc[1]) + b0.y;
        r[2] = fmaf(h2f((unsigned short)(sh.y & 0xffff)), ws, acc[2]) + b0.z;
        r[3] = fmaf(h2f((unsigned short)(sh.y >> 16)),    ws, acc[3]) + b0.w;
        r[4] = fmaf(h2f((unsigned short)(sh.z & 0xffff)), ws, acc[4]) + b1.x;
        r[5] = fmaf(h2f((unsigned short)(sh.z >> 16)),    ws, acc[5]) + b1.y;
        r[6] = fmaf(h2f((unsigned short)(sh.w & 0xffff)), ws, acc[6]) + b1.z;
        r[7] = fmaf(h2f((unsigned short)(sh.w >> 16)),    ws, acc[7]) + b1.w;
#pragma unroll
        for (int i = 0; i < 8; ++i) r[i] = fmaxf(r[i], 0.f);
        uint4 o;
        o.x = (unsigned int)f2h(r[0]) | ((unsigned int)f2h(r[1]) << 16);
        o.y = (unsigned int)f2h(r[2]) | ((unsigned int)f2h(r[3]) << 16);
        o.z = (unsigned int)f2h(r[4]) | ((unsigned int)f2h(r[5]) << 16);
        o.w = (unsigned int)f2h(r[6]) | ((unsigned int)f2h(r[7]) << 16);
        *(uint4*)((unsigned int*)(out + (size_t)half * N_NODES * 128) +
                  (size_t)node * 64 + fl * 4) = o;
    }
}

// ================= pooling (batch sorted) + head =================
__global__ void k_pool(const unsigned short* __restrict__ h2, const int* __restrict__ batch,
                       float* __restrict__ pooled) {
    const int strip = blockIdx.x * 2 + (threadIdx.x >> 7);
    const int tf = threadIdx.x & 127;
    const int f = tf * 2;
    const unsigned short* base = h2 + (size_t)(f >> 7) * N_NODES * 128 + (f & 127);
    const int n0 = strip * 40, n1 = n0 + 40;
    int g = batch[n0];
    float ax = 0.f, ay = 0.f;
    for (int n = n0; n < n1; ++n) {
        const int bg = batch[n];
        if (bg != g) {
            unsafeAtomicAdd(&pooled[g * NFEAT + f], ax);
            unsafeAtomicAdd(&pooled[g * NFEAT + f + 1], ay);
            ax = ay = 0.f;
            g = bg;
        }
        const unsigned int u = *(const unsigned int*)(base + (size_t)n * 128);
        ax += h2f((unsigned short)(u & 0xffff));
        ay += h2f((unsigned short)(u >> 16));
    }
    unsafeAtomicAdd(&pooled[g * NFEAT + f], ax);
    unsafeAtomicAdd(&pooled[g * NFEAT + f + 1], ay);
}

__global__ void k_final(const float* __restrict__ pooled, const float* __restrict__ Wout,
                        const float* __restrict__ bout, float* __restrict__ out) {
    const int g = blockIdx.x, t = threadIdx.x;
    float v = pooled[g * NFEAT + t] * Wout[t];
#pragma unroll
    for (int off = 32; off > 0; off >>= 1) v += __shfl_down(v, off, 64);
    __shared__ float sred[4];
    if ((t & 63) == 0) sred[t >> 6] = v;
    __syncthreads();
    if (t == 0) out[g] = sred[0] + sred[1] + sred[2] + sred[3] + bout[0];
}

extern "C" void kernel_launch(void* const* d_in, const int* in_sizes, int n_in,
                              void* d_out, int out_size, void* d_ws, size_t ws_size,
                              hipStream_t stream) {
    const float* x     = (const float*)d_in[0];
    const int*   ei    = (const int*)d_in[1];
    const int*   batch = (const int*)d_in[2];
    const float* W1    = (const float*)d_in[3];
    const float* b1    = (const float*)d_in[4];
    const float* W2    = (const float*)d_in[5];
    const float* b2    = (const float*)d_in[6];
    const float* Wout  = (const float*)d_in[7];
    const float* bout  = (const float*)d_in[8];
    float* out = (float*)d_out;

    const int* srcp = ei;
    const int* dstp = ei + NEDGE;

    const size_t NE128 = (size_t)N_NODES * 128;  // elements per half-plane
    unsigned short* hA = (unsigned short*)d_ws;            // [2][N][128] fp16
    unsigned short* hB = hA + 2 * NE128;                   // [2][N][128] fp16
    unsigned short* hX = hB + 2 * NE128;                   // [2][N][128] fp16 (x)
    float* dinv      = (float*)(hX + 2 * NE128);           // 50000
    float* pooled    = dinv + N_NODES;                     // 16384
    int*   cnt       = (int*)(pooled + NGRAPH * NFEAT);    // 50000
    int*   row_start = cnt + N_NODES;                      // 50001
    int*   bsum      = row_start + N_NODES + 3;            // 256
    unsigned int* csr = (unsigned int*)(bsum + 256);       // 800000
    int*   rank      = (int*)(csr + NEDGE);                // 800000
    unsigned short* w1t = (unsigned short*)(rank + NEDGE); // 65536 each
    unsigned short* w2t = w1t + 65536;

    const int nblk_edges = (NEDGE + 255) / 256;

    // ---- CSR build (rank-based, single atomic pass) ----
    hipMemsetAsync(cnt, 0, N_NODES * sizeof(int), stream);
    k_count<<<nblk_edges, 256, 0, stream>>>(dstp, cnt, rank);
    k_scan1<<<NBLK_SCAN, 256, 0, stream>>>(cnt, row_start, bsum);
    k_scan2<<<1, 256, 0, stream>>>(bsum);
    k_scan3<<<NBLK_SCAN, 256, 0, stream>>>(row_start, bsum, cnt, dinv);
    k_place<<<nblk_edges, 256, 0, stream>>>(srcp, dstp, rank, row_start, dinv, csr);

    // ---- weight + input prep ----
    k_prep_w<<<512, 256, 0, stream>>>(W1, W2, w1t, w2t);
    k_half_x<<<(N_NODES * 32 + 255) / 256, 256, 0, stream>>>(x, hX);

    const int ggrid = 391;                       // 391 * 128 = 50048 rows
    const int agg_grid = (2 * N_NODES + 3) / 4;  // 25000

    // ---- layer 1 ----
    k_gemm_ws<<<ggrid, 512, 0, stream>>>(hX, w1t, hA, N_NODES);
    k_aggregate<<<agg_grid, 256, 0, stream>>>(hA, row_start, csr, dinv, b1, hB);

    // ---- layer 2 ----
    k_gemm_ws<<<ggrid, 512, 0, stream>>>(hB, w2t, hA, N_NODES);
    k_aggregate<<<agg_grid, 256, 0, stream>>>(hA, row_start, csr, dinv, b2, hB);

    // ---- pooling + head ----
    hipMemsetAsync(pooled, 0, NGRAPH * NFEAT * sizeof(float), stream);
    k_pool<<<625, 256, 0, stream>>>(hB, batch, pooled);
    k_final<<<NGRAPH, 256, 0, stream>>>(pooled, Wout, bout, out);
}

// Round 14
// 290.193 us; speedup vs baseline: 1.0374x; 1.0374x over previous
//
#include <hip/hip_runtime.h>
#include <hip/hip_fp16.h>

#define N_NODES 50000
#define NFEAT   256
#define NGRAPH  64
#define NEDGE   800000
#define NBLK_SCAN 196  // ceil(50000/256)

typedef __attribute__((ext_vector_type(8))) _Float16 half8;
typedef __attribute__((ext_vector_type(2))) _Float16 h2v;
typedef __attribute__((ext_vector_type(4))) float f32x4;
struct alignas(8) US4 { unsigned short x, y, z, w; };

static __device__ __forceinline__ float h2f(unsigned short u) {
    return __half2float(__ushort_as_half(u));
}
static __device__ __forceinline__ unsigned short f2h(float f) {
    return __half_as_ushort(__float2half(f));
}

// ================= CSR build =================
__global__ void k_count(const int* __restrict__ dst, int* __restrict__ cnt) {
    int e = blockIdx.x * 256 + threadIdx.x;
    if (e < NEDGE) atomicAdd(&cnt[dst[e]], 1);
}

__global__ __launch_bounds__(256) void k_scan1(const int* __restrict__ cnt,
                                               int* __restrict__ row_start,
                                               int* __restrict__ bsum) {
    const int t = threadIdx.x, i = blockIdx.x * 256 + t;
    const int lane = t & 63, w = t >> 6;
    const int c = (i < N_NODES) ? cnt[i] : 0;
    int incl = c;
#pragma unroll
    for (int off = 1; off < 64; off <<= 1) {
        int u = __shfl_up(incl, off, 64);
        if (lane >= off) incl += u;
    }
    __shared__ int wtot[4];
    if (lane == 63) wtot[w] = incl;
    __syncthreads();
    int wbase = 0;
#pragma unroll
    for (int k = 0; k < 4; ++k) wbase += (k < w) ? wtot[k] : 0;
    if (i < N_NODES) row_start[i] = wbase + incl - c;
    if (t == 255) bsum[blockIdx.x] = wbase + incl;
}

__global__ __launch_bounds__(256) void k_scan2(int* __restrict__ bsum) {
    const int t = threadIdx.x, lane = t & 63, w = t >> 6;
    const int c = (t < NBLK_SCAN) ? bsum[t] : 0;
    int incl = c;
#pragma unroll
    for (int off = 1; off < 64; off <<= 1) {
        int u = __shfl_up(incl, off, 64);
        if (lane >= off) incl += u;
    }
    __shared__ int wtot[4];
    if (lane == 63) wtot[w] = incl;
    __syncthreads();
    int wbase = 0;
#pragma unroll
    for (int k = 0; k < 4; ++k) wbase += (k < w) ? wtot[k] : 0;
    if (t < NBLK_SCAN) bsum[t] = wbase + incl - c;
}

__global__ void k_scan3(int* __restrict__ row_start, const int* __restrict__ bsum,
                        int* __restrict__ cnt_cursor, float* __restrict__ dinv) {
    const int i = blockIdx.x * 256 + threadIdx.x;
    if (i >= N_NODES) return;
    const int c = cnt_cursor[i];
    const int start = row_start[i] + bsum[blockIdx.x];
    row_start[i] = start;
    cnt_cursor[i] = start;
    dinv[i] = rsqrtf((float)c + 1.0f);
    if (i == 0) row_start[N_NODES] = NEDGE;
}

__global__ void k_place(const int* __restrict__ src, const int* __restrict__ dst,
                        int* __restrict__ cursor, const float* __restrict__ dinv,
                        unsigned int* __restrict__ csr) {
    int e = blockIdx.x * 256 + threadIdx.x;
    if (e < NEDGE) {
        int s = src[e], d = dst[e];
        float norm = dinv[s] * dinv[d];
        int pos = atomicAdd(&cursor[d], 1);
        csr[pos] = ((unsigned int)f2h(norm) << 16) | (unsigned int)s;
    }
}

// ================= W prep: W[k][n] f32 -> Wt [n][k] fp16 =================
__global__ void k_prep_w(const float* __restrict__ W1, const float* __restrict__ W2,
                         unsigned short* __restrict__ w1t, unsigned short* __restrict__ w2t) {
    const int l = blockIdx.x >> 8;
    const int idx = (blockIdx.x & 255) * 256 + threadIdx.x;
    const int n = idx >> 8, k = idx & 255;
    const float* W = l ? W2 : W1;
    unsigned short* wt = l ? w2t : w1t;
    wt[n * 256 + k] = f2h(W[k * 256 + n]);
}

// ================= fp16 MFMA GEMM: C[half][node][128] = A[M,256] @ W =================
// Barrier-free main loop: FULL B-half (64KB) staged once, ONE barrier, then each
// wave streams 32 A-rows (2 chunks of 16) with register ping-pong.
// Grid (391, 2) = 782 blocks (128 rows each) for balance + TLP at 2 blocks/CU.
template <bool AF32>
__global__ __launch_bounds__(256) void k_gemm_mfma(const float* __restrict__ Af,
                                                   const unsigned short* __restrict__ Ah,
                                                   const unsigned short* __restrict__ Wt,
                                                   unsigned short* __restrict__ Ch, int M) {
    __shared__ unsigned short lds[32768];  // [ks(8)][n(128)][32k] swizzled k-groups
    const int t = threadIdx.x;
    const int half = blockIdx.y;
    const int m0 = blockIdx.x * 128;
    const int w = t >> 6, lane = t & 63;
    const int lr = lane & 15, g = lane >> 4;

    // ---- stage full B-half into LDS (once) ----
    {
        const unsigned short* wbase = Wt + (size_t)half * 128 * 256;
#pragma unroll
        for (int it = 0; it < 16; ++it) {
            const int unit = it * 256 + t;    // 0..4095 16B-units
            const int n = unit >> 5;          // 0..127
            const int rem = unit & 31;        // 32 units per row
            const int ks = rem >> 2, kg = rem & 3;
            const half8 v = *(const half8*)&wbase[n * 256 + rem * 8];
            const int kgx = kg ^ ((n >> 1) & 3);
            *(half8*)&lds[ks * 4096 + n * 32 + kgx * 8] = v;
        }
    }
    __syncthreads();  // the ONLY barrier

    const int rbase = m0 + w * 32;
    unsigned short* Chh = Ch + (size_t)half * (size_t)N_NODES * 128;

    half8 aA[8], aB[8];

#define LOADCHUNK(C, DST)                                                                \
    {                                                                                    \
        const int row = min(rbase + (C) * 16 + lr, M - 1);                               \
        _Pragma("unroll") for (int ks = 0; ks < 8; ++ks) {                               \
            if (AF32) {                                                                  \
                const float* ap = Af + (size_t)row * 256 + ks * 32 + g * 8;              \
                const float4 p0 = *(const float4*)ap;                                    \
                const float4 p1 = *(const float4*)(ap + 4);                              \
                half8 h;                                                                 \
                h[0] = (_Float16)p0.x; h[1] = (_Float16)p0.y;                            \
                h[2] = (_Float16)p0.z; h[3] = (_Float16)p0.w;                            \
                h[4] = (_Float16)p1.x; h[5] = (_Float16)p1.y;                            \
                h[6] = (_Float16)p1.z; h[7] = (_Float16)p1.w;                            \
                DST[ks] = h;                                                             \
            } else {                                                                     \
                DST[ks] = *(const half8*)(Ah + (size_t)(ks >> 2) * (size_t)N_NODES * 128 \
                                          + (size_t)row * 128 + (ks & 3) * 32 + g * 8);  \
            }                                                                            \
        }                                                                                \
    }

#define COMPUTE(C, SRC)                                                                  \
    {                                                                                    \
        f32x4 acc[8] = {};                                                               \
        _Pragma("unroll") for (int ks = 0; ks < 8; ++ks) {                               \
            _Pragma("unroll") for (int ni = 0; ni < 8; ++ni) {                           \
                const int n = ni * 16 + lr;                                              \
                const half8 bf = *(const half8*)&lds[ks * 4096 + n * 32 +                \
                                                     ((g ^ ((n >> 1) & 3)) << 3)];       \
                acc[ni] = __builtin_amdgcn_mfma_f32_16x16x32_f16(SRC[ks], bf,            \
                                                                 acc[ni], 0, 0, 0);      \
            }                                                                            \
        }                                                                                \
        const int r0 = rbase + (C) * 16 + g * 4;                                         \
        _Pragma("unroll") for (int ni = 0; ni < 8; ++ni) {                               \
            const int col = ni * 16 + lr;                                                \
            _Pragma("unroll") for (int r = 0; r < 4; ++r) {                              \
                if (r0 + r < M) Chh[(size_t)(r0 + r) * 128 + col] = f2h(acc[ni][r]);     \
            }                                                                            \
        }                                                                                \
    }

    LOADCHUNK(0, aA)
    LOADCHUNK(1, aB)
    COMPUTE(0, aA)
    COMPUTE(1, aB)

#undef LOADCHUNK
#undef COMPUTE
}

// ================= aggregation: one dispatch per feature-half =================
// wave per node; 16 lanes/edge; fdot2 packing 2 edges x 2 feats per instruction.
__global__ __launch_bounds__(256) void k_aggregate(const unsigned short* __restrict__ h16,
                                                   const int* __restrict__ row_start,
                                                   const unsigned int* __restrict__ csr,
                                                   const float* __restrict__ dinv,
                                                   const float* __restrict__ bias,
                                                   unsigned short* __restrict__ out,
                                                   const int half) {
    const int node = blockIdx.x * 4 + (threadIdx.x >> 6);
    if (node >= N_NODES) return;
    const int lane = threadIdx.x & 63;
    const int sub = lane >> 4;   // 0..3: edge-pair index
    const int fl = lane & 15;    // 8 feats per lane
    const unsigned int* hu = (const unsigned int*)(h16 + (size_t)half * N_NODES * 128);

    float acc[8] = {};
    const int s0 = row_start[node], s1 = row_start[node + 1];
    const unsigned int* row = csr + s0;
    const int n = s1 - s0;

#define EDGEPAIR(EA, EB)                                                              \
    {                                                                                 \
        const unsigned int wnp = __builtin_amdgcn_perm(EB, EA, 0x07060302u);          \
        const h2v wn2 = __builtin_bit_cast(h2v, wnp);                                 \
        const uint4 va = *(const uint4*)(hu + (size_t)((EA)&0xffffu) * 64 + fl * 4);  \
        const uint4 vb = *(const uint4*)(hu + (size_t)((EB)&0xffffu) * 64 + fl * 4);  \
        unsigned int plo, phi;                                                        \
        plo = __builtin_amdgcn_perm(vb.x, va.x, 0x05040100u);                         \
        phi = __builtin_amdgcn_perm(vb.x, va.x, 0x07060302u);                         \
        acc[0] = __builtin_amdgcn_fdot2(__builtin_bit_cast(h2v, plo), wn2, acc[0], false); \
        acc[1] = __builtin_amdgcn_fdot2(__builtin_bit_cast(h2v, phi), wn2, acc[1], false); \
        plo = __builtin_amdgcn_perm(vb.y, va.y, 0x05040100u);                         \
        phi = __builtin_amdgcn_perm(vb.y, va.y, 0x07060302u);                         \
        acc[2] = __builtin_amdgcn_fdot2(__builtin_bit_cast(h2v, plo), wn2, acc[2], false); \
        acc[3] = __builtin_amdgcn_fdot2(__builtin_bit_cast(h2v, phi), wn2, acc[3], false); \
        plo = __builtin_amdgcn_perm(vb.z, va.z, 0x05040100u);                         \
        phi = __builtin_amdgcn_perm(vb.z, va.z, 0x07060302u);                         \
        acc[4] = __builtin_amdgcn_fdot2(__builtin_bit_cast(h2v, plo), wn2, acc[4], false); \
        acc[5] = __builtin_amdgcn_fdot2(__builtin_bit_cast(h2v, phi), wn2, acc[5], false); \
        plo = __builtin_amdgcn_perm(vb.w, va.w, 0x05040100u);                         \
        phi = __builtin_amdgcn_perm(vb.w, va.w, 0x07060302u);                         \
        acc[6] = __builtin_amdgcn_fdot2(__builtin_bit_cast(h2v, plo), wn2, acc[6], false); \
        acc[7] = __builtin_amdgcn_fdot2(__builtin_bit_cast(h2v, phi), wn2, acc[7], false); \
    }

    const int nfull = n & ~7;
    int j = 0;
    for (; j < nfull; j += 8) {
        const unsigned int ea = row[j + sub * 2];
        const unsigned int eb = row[j + sub * 2 + 1];
        EDGEPAIR(ea, eb)
    }
    if (j < n) {  // guarded tail (invalid slots: e=0 -> wn=0 -> contributes 0)
        const int ia = j + sub * 2, ib = ia + 1;
        const unsigned int ea = (ia < n) ? row[ia] : 0u;
        const unsigned int eb = (ib < n) ? row[ib] : 0u;
        EDGEPAIR(ea, eb)
    }
#undef EDGEPAIR

#pragma unroll
    for (int i = 0; i < 8; ++i) {
        acc[i] += __shfl_xor(acc[i], 16, 64);
        acc[i] += __shfl_xor(acc[i], 32, 64);
    }

    if (sub == 0) {  // lanes 0-15 hold the final sums
        const float dd = dinv[node];
        const float ws = dd * dd;
        const uint4 sh = *(const uint4*)(hu + (size_t)node * 64 + fl * 4);
        const float4 b0 = *(const float4*)(bias + half * 128 + fl * 8);
        const float4 b1 = *(const float4*)(bias + half * 128 + fl * 8 + 4);
        float r[8];
        r[0] = fmaf(h2f((unsigned short)(sh.x & 0xffff)), ws, acc[0]) + b0.x;
        r[1] = fmaf(h2f((unsigned short)(sh.x >> 16)),    ws, acc[1]) + b0.y;
        r[2] = fmaf(h2f((unsigned short)(sh.y & 0xffff)), ws, acc[2]) + b0.z;
        r[3] = fmaf(h2f((unsigned short)(sh.y >> 16)),    ws, acc[3]) + b0.w;
        r[4] = fmaf(h2f((unsigned short)(sh.z & 0xffff)), ws, acc[4]) + b1.x;
        r[5] = fmaf(h2f((unsigned short)(sh.z >> 16)),    ws, acc[5]) + b1.y;
        r[6] = fmaf(h2f((unsigned short)(sh.w & 0xffff)), ws, acc[6]) + b1.z;
        r[7] = fmaf(h2f((unsigned short)(sh.w >> 16)),    ws, acc[7]) + b1.w;
#pragma unroll
        for (int i = 0; i < 8; ++i) r[i] = fmaxf(r[i], 0.f);
        uint4 o;
        o.x = (unsigned int)f2h(r[0]) | ((unsigned int)f2h(r[1]) << 16);
        o.y = (unsigned int)f2h(r[2]) | ((unsigned int)f2h(r[3]) << 16);
        o.z = (unsigned int)f2h(r[4]) | ((unsigned int)f2h(r[5]) << 16);
        o.w = (unsigned int)f2h(r[6]) | ((unsigned int)f2h(r[7]) << 16);
        *(uint4*)((unsigned int*)(out + (size_t)half * N_NODES * 128) +
                  (size_t)node * 64 + fl * 4) = o;
    }
}

// ================= pooling (batch sorted) + head =================
__global__ void k_pool(const unsigned short* __restrict__ h2, const int* __restrict__ batch,
                       float* __restrict__ pooled) {
    const int strip = blockIdx.x * 2 + (threadIdx.x >> 7);
    const int tf = threadIdx.x & 127;
    const int f = tf * 2;
    const unsigned short* base = h2 + (size_t)(f >> 7) * N_NODES * 128 + (f & 127);
    const int n0 = strip * 40, n1 = n0 + 40;
    int g = batch[n0];
    float ax = 0.f, ay = 0.f;
    for (int n = n0; n < n1; ++n) {
        const int bg = batch[n];
        if (bg != g) {
            unsafeAtomicAdd(&pooled[g * NFEAT + f], ax);
            unsafeAtomicAdd(&pooled[g * NFEAT + f + 1], ay);
            ax = ay = 0.f;
            g = bg;
        }
        const unsigned int u = *(const unsigned int*)(base + (size_t)n * 128);
        ax += h2f((unsigned short)(u & 0xffff));
        ay += h2f((unsigned short)(u >> 16));
    }
    unsafeAtomicAdd(&pooled[g * NFEAT + f], ax);
    unsafeAtomicAdd(&pooled[g * NFEAT + f + 1], ay);
}

__global__ void k_final(const float* __restrict__ pooled, const float* __restrict__ Wout,
                        const float* __restrict__ bout, float* __restrict__ out) {
    const int g = blockIdx.x, t = threadIdx.x;
    float v = pooled[g * NFEAT + t] * Wout[t];
#pragma unroll
    for (int off = 32; off > 0; off >>= 1) v += __shfl_down(v, off, 64);
    __shared__ float sred[4];
    if ((t & 63) == 0) sred[t >> 6] = v;
    __syncthreads();
    if (t == 0) out[g] = sred[0] + sred[1] + sred[2] + sred[3] + bout[0];
}

extern "C" void kernel_launch(void* const* d_in, const int* in_sizes, int n_in,
                              void* d_out, int out_size, void* d_ws, size_t ws_size,
                              hipStream_t stream) {
    const float* x     = (const float*)d_in[0];
    const int*   ei    = (const int*)d_in[1];
    const int*   batch = (const int*)d_in[2];
    const float* W1    = (const float*)d_in[3];
    const float* b1    = (const float*)d_in[4];
    const float* W2    = (const float*)d_in[5];
    const float* b2    = (const float*)d_in[6];
    const float* Wout  = (const float*)d_in[7];
    const float* bout  = (const float*)d_in[8];
    float* out = (float*)d_out;

    const int* srcp = ei;
    const int* dstp = ei + NEDGE;

    const size_t NE128 = (size_t)N_NODES * 128;  // elements per half-plane
    unsigned short* hA = (unsigned short*)d_ws;            // [2][N][128] fp16
    unsigned short* hB = hA + 2 * NE128;                   // [2][N][128] fp16
    float* dinv      = (float*)(hB + 2 * NE128);           // 50000
    float* pooled    = dinv + N_NODES;                     // 16384
    int*   cnt       = (int*)(pooled + NGRAPH * NFEAT);    // 50000 (doubles as cursor)
    int*   row_start = cnt + N_NODES;                      // 50001
    int*   bsum      = row_start + N_NODES + 3;            // 256
    unsigned int* csr = (unsigned int*)(bsum + 256);       // 800000
    unsigned short* w1t = (unsigned short*)(csr + NEDGE);  // 65536 each
    unsigned short* w2t = w1t + 65536;

    const int nblk_edges = (NEDGE + 255) / 256;

    // ---- CSR build ----
    hipMemsetAsync(cnt, 0, N_NODES * sizeof(int), stream);
    k_count<<<nblk_edges, 256, 0, stream>>>(dstp, cnt);
    k_scan1<<<NBLK_SCAN, 256, 0, stream>>>(cnt, row_start, bsum);
    k_scan2<<<1, 256, 0, stream>>>(bsum);
    k_scan3<<<NBLK_SCAN, 256, 0, stream>>>(row_start, bsum, cnt, dinv);
    k_place<<<nblk_edges, 256, 0, stream>>>(srcp, dstp, cnt, dinv, csr);

    // ---- weight prep ----
    k_prep_w<<<512, 256, 0, stream>>>(W1, W2, w1t, w2t);

    const dim3 ggrid(391, 2);                    // 391 x 128 rows x 2 halves
    const int agg_grid = (N_NODES + 3) / 4;      // 12500 per half

    // ---- layer 1 (x f32 -> fp16 fused into GEMM A-load) ----
    k_gemm_mfma<true><<<ggrid, 256, 0, stream>>>(x, nullptr, w1t, hA, N_NODES);
    k_aggregate<<<agg_grid, 256, 0, stream>>>(hA, row_start, csr, dinv, b1, hB, 0);
    k_aggregate<<<agg_grid, 256, 0, stream>>>(hA, row_start, csr, dinv, b1, hB, 1);

    // ---- layer 2 ----
    k_gemm_mfma<false><<<ggrid, 256, 0, stream>>>(nullptr, hB, w2t, hA, N_NODES);
    k_aggregate<<<agg_grid, 256, 0, stream>>>(hA, row_start, csr, dinv, b2, hB, 0);
    k_aggregate<<<agg_grid, 256, 0, stream>>>(hA, row_start, csr, dinv, b2, hB, 1);

    // ---- pooling + head ----
    hipMemsetAsync(pooled, 0, NGRAPH * NFEAT * sizeof(float), stream);
    k_pool<<<625, 256, 0, stream>>>(hB, batch, pooled);
    k_final<<<NGRAPH, 256, 0, stream>>>(pooled, Wout, bout, out);
}

// Round 15
// 277.136 us; speedup vs baseline: 1.0863x; 1.0471x over previous
//
#include <hip/hip_runtime.h>
#include <hip/hip_fp16.h>

#define N_NODES 50000
#define NFEAT   256
#define NGRAPH  64
#define NEDGE   800000
#define NBUCK   98      // ceil(50000/512) buckets of 512 nodes
#define BWIN    16384   // fixed tmp window per bucket (mean 8163, sigma~90)

typedef __attribute__((ext_vector_type(8))) _Float16 half8;
typedef __attribute__((ext_vector_type(2))) _Float16 h2v;
typedef __attribute__((ext_vector_type(4))) float f32x4;
struct alignas(8) US4 { unsigned short x, y, z, w; };

static __device__ __forceinline__ float h2f(unsigned short u) {
    return __half2float(__ushort_as_half(u));
}
static __device__ __forceinline__ unsigned short f2h(float f) {
    return __half_as_ushort(__float2half(f));
}

// ================= CSR build, phase A: bin edges into buckets =================
__global__ __launch_bounds__(256) void k_bin(const int* __restrict__ src,
                                             const int* __restrict__ dst,
                                             int* __restrict__ bcnt,
                                             unsigned int* __restrict__ tmp) {
    __shared__ int hist[NBUCK];
    __shared__ int base[NBUCK];
    const int t = threadIdx.x;
    if (t < NBUCK) hist[t] = 0;
    __syncthreads();
    const int e0 = blockIdx.x * 1024 + t * 4;
    int s[4], d[4], b[4], rk[4];
#pragma unroll
    for (int i = 0; i < 4; ++i) {
        const int e = e0 + i;
        if (e < NEDGE) {
            s[i] = src[e];
            d[i] = dst[e];
            b[i] = d[i] >> 9;
            rk[i] = atomicAdd(&hist[b[i]], 1);
        } else {
            b[i] = -1;
        }
    }
    __syncthreads();
    if (t < NBUCK) base[t] = atomicAdd(&bcnt[t], hist[t]);
    __syncthreads();
#pragma unroll
    for (int i = 0; i < 4; ++i) {
        if (b[i] >= 0)
            tmp[(size_t)b[i] * BWIN + base[b[i]] + rk[i]] =
                ((unsigned int)s[i] << 16) | (unsigned int)d[i];
    }
}

// ================= phase A.5: exclusive scan of bucket totals (1 wave) =================
__global__ void k_bscan(const int* __restrict__ bcnt, int* __restrict__ bbase) {
    const int l = threadIdx.x;  // 64 lanes, lane l owns buckets 2l, 2l+1
    const int i0 = 2 * l, i1 = 2 * l + 1;
    const int v0 = (i0 < NBUCK) ? bcnt[i0] : 0;
    const int v1 = (i1 < NBUCK) ? bcnt[i1] : 0;
    const int ps = v0 + v1;
    int incl = ps;
#pragma unroll
    for (int off = 1; off < 64; off <<= 1) {
        int u = __shfl_up(incl, off, 64);
        if (l >= off) incl += u;
    }
    const int excl = incl - ps;
    if (i0 < NBUCK) bbase[i0] = excl;
    if (i1 < NBUCK) bbase[i1] = excl + v0;
}

// ================= phase B: per-bucket local count/scan/place =================
// writes row_start, dinv, and csr (src-only ushort) with XCD-local 16KB scatter.
__global__ __launch_bounds__(256) void k_build(const unsigned int* __restrict__ tmp,
                                               const int* __restrict__ bcnt,
                                               const int* __restrict__ bbase,
                                               int* __restrict__ row_start,
                                               float* __restrict__ dinv,
                                               unsigned short* __restrict__ csr) {
    __shared__ int cnt[512];
    __shared__ int cur[512];
    __shared__ int wtot[4];
    const int bk = blockIdx.x, t = threadIdx.x;
    const int node0 = bk << 9;
    const int n = bcnt[bk];
    const unsigned int* rec = tmp + (size_t)bk * BWIN;
    cnt[t] = 0;
    cnt[t + 256] = 0;
    __syncthreads();
    for (int i = t; i < n; i += 256) atomicAdd(&cnt[rec[i] & 511], 1);
    __syncthreads();
    // exclusive scan of cnt[512]: thread t owns pair (2t, 2t+1)
    const int lane = t & 63, w = t >> 6;
    const int v0 = cnt[2 * t], v1 = cnt[2 * t + 1];
    const int ps = v0 + v1;
    int incl = ps;
#pragma unroll
    for (int off = 1; off < 64; off <<= 1) {
        int u = __shfl_up(incl, off, 64);
        if (lane >= off) incl += u;
    }
    if (lane == 63) wtot[w] = incl;
    __syncthreads();
    int wbase = 0;
#pragma unroll
    for (int k = 0; k < 4; ++k) wbase += (k < w) ? wtot[k] : 0;
    const int excl = wbase + incl - ps;
    const int gb = bbase[bk];
    const int g0 = node0 + 2 * t;
    if (g0 < N_NODES) {
        row_start[g0] = gb + excl;
        dinv[g0] = rsqrtf((float)v0 + 1.0f);
    }
    if (g0 + 1 < N_NODES) {
        row_start[g0 + 1] = gb + excl + v0;
        dinv[g0 + 1] = rsqrtf((float)v1 + 1.0f);
    }
    cur[2 * t] = gb + excl;
    cur[2 * t + 1] = gb + excl + v0;
    __syncthreads();
    for (int i = t; i < n; i += 256) {
        const unsigned int r = rec[i];
        const int pos = atomicAdd(&cur[r & 511], 1);
        csr[pos] = (unsigned short)(r >> 16);  // src only
    }
    if (bk == 0 && t == 0) row_start[N_NODES] = NEDGE;
}

// ================= W prep: W[k][n] f32 -> Wt [n][k] fp16 =================
__global__ void k_prep_w(const float* __restrict__ W1, const float* __restrict__ W2,
                         unsigned short* __restrict__ w1t, unsigned short* __restrict__ w2t) {
    const int l = blockIdx.x >> 8;
    const int idx = (blockIdx.x & 255) * 256 + threadIdx.x;
    const int n = idx >> 8, k = idx & 255;
    const float* W = l ? W2 : W1;
    unsigned short* wt = l ? w2t : w1t;
    wt[n * 256 + k] = f2h(W[k * 256 + n]);
}

// ================= fp16 MFMA GEMM: Chs[half][node][128] = dinv .* (A @ W) ==========
// Full B-half (64KB) staged once, ONE barrier; wave streams 32 A-rows.
// Epilogue scales row r by dinv[r] (norm factorization).
template <bool AF32>
__global__ __launch_bounds__(256) void k_gemm_mfma(const float* __restrict__ Af,
                                                   const unsigned short* __restrict__ Ah,
                                                   const unsigned short* __restrict__ Wt,
                                                   const float* __restrict__ dinv,
                                                   unsigned short* __restrict__ Ch, int M) {
    __shared__ unsigned short lds[32768];  // [ks(8)][n(128)][32k] swizzled k-groups
    const int t = threadIdx.x;
    const int half = blockIdx.y;
    const int m0 = blockIdx.x * 128;
    const int w = t >> 6, lane = t & 63;
    const int lr = lane & 15, g = lane >> 4;

    {
        const unsigned short* wbase = Wt + (size_t)half * 128 * 256;
#pragma unroll
        for (int it = 0; it < 16; ++it) {
            const int unit = it * 256 + t;
            const int n = unit >> 5;
            const int rem = unit & 31;
            const int ks = rem >> 2, kg = rem & 3;
            const half8 v = *(const half8*)&wbase[n * 256 + rem * 8];
            const int kgx = kg ^ ((n >> 1) & 3);
            *(half8*)&lds[ks * 4096 + n * 32 + kgx * 8] = v;
        }
    }
    __syncthreads();  // the ONLY barrier

    const int rbase = m0 + w * 32;
    unsigned short* Chh = Ch + (size_t)half * (size_t)N_NODES * 128;

    half8 aA[8], aB[8];

#define LOADCHUNK(C, DST)                                                                \
    {                                                                                    \
        const int row = min(rbase + (C) * 16 + lr, M - 1);                               \
        _Pragma("unroll") for (int ks = 0; ks < 8; ++ks) {                               \
            if (AF32) {                                                                  \
                const float* ap = Af + (size_t)row * 256 + ks * 32 + g * 8;              \
                const float4 p0 = *(const float4*)ap;                                    \
                const float4 p1 = *(const float4*)(ap + 4);                              \
                half8 h;                                                                 \
                h[0] = (_Float16)p0.x; h[1] = (_Float16)p0.y;                            \
                h[2] = (_Float16)p0.z; h[3] = (_Float16)p0.w;                            \
                h[4] = (_Float16)p1.x; h[5] = (_Float16)p1.y;                            \
                h[6] = (_Float16)p1.z; h[7] = (_Float16)p1.w;                            \
                DST[ks] = h;                                                             \
            } else {                                                                     \
                DST[ks] = *(const half8*)(Ah + (size_t)(ks >> 2) * (size_t)N_NODES * 128 \
                                          + (size_t)row * 128 + (ks & 3) * 32 + g * 8);  \
            }                                                                            \
        }                                                                                \
    }

#define COMPUTE(C, SRC)                                                                  \
    {                                                                                    \
        f32x4 acc[8] = {};                                                               \
        _Pragma("unroll") for (int ks = 0; ks < 8; ++ks) {                               \
            _Pragma("unroll") for (int ni = 0; ni < 8; ++ni) {                           \
                const int n = ni * 16 + lr;                                              \
                const half8 bf = *(const half8*)&lds[ks * 4096 + n * 32 +                \
                                                     ((g ^ ((n >> 1) & 3)) << 3)];       \
                acc[ni] = __builtin_amdgcn_mfma_f32_16x16x32_f16(SRC[ks], bf,            \
                                                                 acc[ni], 0, 0, 0);      \
            }                                                                            \
        }                                                                                \
        const int r0 = rbase + (C) * 16 + g * 4;                                         \
        float dv[4];                                                                     \
        _Pragma("unroll") for (int r = 0; r < 4; ++r)                                    \
            dv[r] = dinv[min(r0 + r, M - 1)];                                            \
        _Pragma("unroll") for (int ni = 0; ni < 8; ++ni) {                               \
            const int col = ni * 16 + lr;                                                \
            _Pragma("unroll") for (int r = 0; r < 4; ++r) {                              \
                if (r0 + r < M)                                                          \
                    Chh[(size_t)(r0 + r) * 128 + col] = f2h(acc[ni][r] * dv[r]);         \
            }                                                                            \
        }                                                                                \
    }

    LOADCHUNK(0, aA)
    LOADCHUNK(1, aB)
    COMPUTE(0, aA)
    COMPUTE(1, aB)

#undef LOADCHUNK
#undef COMPUTE
}

// ================= aggregation: out[d] = relu(b + dinv[d]*(hs[d] + sum hs[s])) =========
// csr = src-only ushort; weight-free gather (fdot2 with ones); one dispatch per half.
__global__ __launch_bounds__(256) void k_aggregate(const unsigned short* __restrict__ hs,
                                                   const int* __restrict__ row_start,
                                                   const unsigned short* __restrict__ csr,
                                                   const float* __restrict__ dinv,
                                                   const float* __restrict__ bias,
                                                   unsigned short* __restrict__ out,
                                                   const int half) {
    const int node = blockIdx.x * 4 + (threadIdx.x >> 6);
    if (node >= N_NODES) return;
    const int lane = threadIdx.x & 63;
    const int sub = lane >> 4;   // 0..3: edge-pair index
    const int fl = lane & 15;    // 8 feats per lane
    const unsigned int* hu = (const unsigned int*)(hs + (size_t)half * N_NODES * 128);
    const h2v one2 = {(_Float16)1.0f, (_Float16)1.0f};

    float acc[8] = {};
    const int s0 = row_start[node], s1 = row_start[node + 1];
    const unsigned short* row = csr + s0;
    const int n = s1 - s0;

#define EDGEPAIR(VA, VB)                                                                   \
    {                                                                                      \
        unsigned int plo, phi;                                                             \
        plo = __builtin_amdgcn_perm(VB.x, VA.x, 0x05040100u);                              \
        phi = __builtin_amdgcn_perm(VB.x, VA.x, 0x07060302u);                              \
        acc[0] = __builtin_amdgcn_fdot2(__builtin_bit_cast(h2v, plo), one2, acc[0], false);\
        acc[1] = __builtin_amdgcn_fdot2(__builtin_bit_cast(h2v, phi), one2, acc[1], false);\
        plo = __builtin_amdgcn_perm(VB.y, VA.y, 0x05040100u);                              \
        phi = __builtin_amdgcn_perm(VB.y, VA.y, 0x07060302u);                              \
        acc[2] = __builtin_amdgcn_fdot2(__builtin_bit_cast(h2v, plo), one2, acc[2], false);\
        acc[3] = __builtin_amdgcn_fdot2(__builtin_bit_cast(h2v, phi), one2, acc[3], false);\
        plo = __builtin_amdgcn_perm(VB.z, VA.z, 0x05040100u);                              \
        phi = __builtin_amdgcn_perm(VB.z, VA.z, 0x07060302u);                              \
        acc[4] = __builtin_amdgcn_fdot2(__builtin_bit_cast(h2v, plo), one2, acc[4], false);\
        acc[5] = __builtin_amdgcn_fdot2(__builtin_bit_cast(h2v, phi), one2, acc[5], false);\
        plo = __builtin_amdgcn_perm(VB.w, VA.w, 0x05040100u);                              \
        phi = __builtin_amdgcn_perm(VB.w, VA.w, 0x07060302u);                              \
        acc[6] = __builtin_amdgcn_fdot2(__builtin_bit_cast(h2v, plo), one2, acc[6], false);\
        acc[7] = __builtin_amdgcn_fdot2(__builtin_bit_cast(h2v, phi), one2, acc[7], false);\
    }

    const int nfull = n & ~7;
    int j = 0;
    for (; j < nfull; j += 8) {
        const int sa = row[j + sub * 2];
        const int sb = row[j + sub * 2 + 1];
        const uint4 va = *(const uint4*)(hu + (size_t)sa * 64 + fl * 4);
        const uint4 vb = *(const uint4*)(hu + (size_t)sb * 64 + fl * 4);
        EDGEPAIR(va, vb)
    }
    if (j < n) {  // guarded tail: invalid slots contribute zero vectors
        const int ia = j + sub * 2, ib = ia + 1;
        uint4 va = {0, 0, 0, 0}, vb = {0, 0, 0, 0};
        if (ia < n) va = *(const uint4*)(hu + (size_t)row[ia] * 64 + fl * 4);
        if (ib < n) vb = *(const uint4*)(hu + (size_t)row[ib] * 64 + fl * 4);
        EDGEPAIR(va, vb)
    }
#undef EDGEPAIR

#pragma unroll
    for (int i = 0; i < 8; ++i) {
        acc[i] += __shfl_xor(acc[i], 16, 64);
        acc[i] += __shfl_xor(acc[i], 32, 64);
    }

    if (sub == 0) {  // lanes 0-15 hold the final sums
        const float dd = dinv[node];
        const uint4 sh = *(const uint4*)(hu + (size_t)node * 64 + fl * 4);
        const float4 b0 = *(const float4*)(bias + half * 128 + fl * 8);
        const float4 b1 = *(const float4*)(bias + half * 128 + fl * 8 + 4);
        float r[8];
        r[0] = fmaf(acc[0] + h2f((unsigned short)(sh.x & 0xffff)), dd, b0.x);
        r[1] = fmaf(acc[1] + h2f((unsigned short)(sh.x >> 16)),    dd, b0.y);
        r[2] = fmaf(acc[2] + h2f((unsigned short)(sh.y & 0xffff)), dd, b0.z);
        r[3] = fmaf(acc[3] + h2f((unsigned short)(sh.y >> 16)),    dd, b0.w);
        r[4] = fmaf(acc[4] + h2f((unsigned short)(sh.z & 0xffff)), dd, b1.x);
        r[5] = fmaf(acc[5] + h2f((unsigned short)(sh.z >> 16)),    dd, b1.y);
        r[6] = fmaf(acc[6] + h2f((unsigned short)(sh.w & 0xffff)), dd, b1.z);
        r[7] = fmaf(acc[7] + h2f((unsigned short)(sh.w >> 16)),    dd, b1.w);
#pragma unroll
        for (int i = 0; i < 8; ++i) r[i] = fmaxf(r[i], 0.f);
        uint4 o;
        o.x = (unsigned int)f2h(r[0]) | ((unsigned int)f2h(r[1]) << 16);
        o.y = (unsigned int)f2h(r[2]) | ((unsigned int)f2h(r[3]) << 16);
        o.z = (unsigned int)f2h(r[4]) | ((unsigned int)f2h(r[5]) << 16);
        o.w = (unsigned int)f2h(r[6]) | ((unsigned int)f2h(r[7]) << 16);
        *(uint4*)((unsigned int*)(out + (size_t)half * N_NODES * 128) +
                  (size_t)node * 64 + fl * 4) = o;
    }
}

// ================= pooling (batch sorted) + head =================
__global__ void k_pool(const unsigned short* __restrict__ h2, const int* __restrict__ batch,
                       float* __restrict__ pooled) {
    const int strip = blockIdx.x * 2 + (threadIdx.x >> 7);
    const int tf = threadIdx.x & 127;
    const int f = tf * 2;
    const unsigned short* base = h2 + (size_t)(f >> 7) * N_NODES * 128 + (f & 127);
    const int n0 = strip * 40, n1 = n0 + 40;
    int g = batch[n0];
    float ax = 0.f, ay = 0.f;
    for (int n = n0; n < n1; ++n) {
        const int bg = batch[n];
        if (bg != g) {
            unsafeAtomicAdd(&pooled[g * NFEAT + f], ax);
            unsafeAtomicAdd(&pooled[g * NFEAT + f + 1], ay);
            ax = ay = 0.f;
            g = bg;
        }
        const unsigned int u = *(const unsigned int*)(base + (size_t)n * 128);
        ax += h2f((unsigned short)(u & 0xffff));
        ay += h2f((unsigned short)(u >> 16));
    }
    unsafeAtomicAdd(&pooled[g * NFEAT + f], ax);
    unsafeAtomicAdd(&pooled[g * NFEAT + f + 1], ay);
}

__global__ void k_final(const float* __restrict__ pooled, const float* __restrict__ Wout,
                        const float* __restrict__ bout, float* __restrict__ out) {
    const int g = blockIdx.x, t = threadIdx.x;
    float v = pooled[g * NFEAT + t] * Wout[t];
#pragma unroll
    for (int off = 32; off > 0; off >>= 1) v += __shfl_down(v, off, 64);
    __shared__ float sred[4];
    if ((t & 63) == 0) sred[t >> 6] = v;
    __syncthreads();
    if (t == 0) out[g] = sred[0] + sred[1] + sred[2] + sred[3] + bout[0];
}

extern "C" void kernel_launch(void* const* d_in, const int* in_sizes, int n_in,
                              void* d_out, int out_size, void* d_ws, size_t ws_size,
                              hipStream_t stream) {
    const float* x     = (const float*)d_in[0];
    const int*   ei    = (const int*)d_in[1];
    const int*   batch = (const int*)d_in[2];
    const float* W1    = (const float*)d_in[3];
    const float* b1    = (const float*)d_in[4];
    const float* W2    = (const float*)d_in[5];
    const float* b2    = (const float*)d_in[6];
    const float* Wout  = (const float*)d_in[7];
    const float* bout  = (const float*)d_in[8];
    float* out = (float*)d_out;

    const int* srcp = ei;
    const int* dstp = ei + NEDGE;

    const size_t NE128 = (size_t)N_NODES * 128;  // elements per half-plane
    unsigned short* hA = (unsigned short*)d_ws;            // [2][N][128] fp16 (dinv-scaled)
    unsigned short* hB = hA + 2 * NE128;                   // [2][N][128] fp16
    float* dinv      = (float*)(hB + 2 * NE128);           // 50000
    float* pooled    = dinv + N_NODES;                     // 16384
    int*   row_start = (int*)(pooled + NGRAPH * NFEAT);    // 50001 (+pad)
    int*   bcnt      = row_start + N_NODES + 3;            // 98
    int*   bbase     = bcnt + NBUCK;                       // 98
    unsigned short* csr = (unsigned short*)(bbase + NBUCK);// 800000 ushort (1.6MB)
    unsigned int* tmp = (unsigned int*)(csr + NEDGE);      // 98*16384 uint (6.4MB)
    unsigned short* w1t = (unsigned short*)(tmp + (size_t)NBUCK * BWIN);  // 65536 each
    unsigned short* w2t = w1t + 65536;

    // ---- CSR build: bucketed two-phase ----
    hipMemsetAsync(bcnt, 0, NBUCK * sizeof(int), stream);
    k_bin<<<(NEDGE + 1023) / 1024, 256, 0, stream>>>(srcp, dstp, bcnt, tmp);
    k_bscan<<<1, 64, 0, stream>>>(bcnt, bbase);
    k_build<<<NBUCK, 256, 0, stream>>>(tmp, bcnt, bbase, row_start, dinv, csr);

    // ---- weight prep ----
    k_prep_w<<<512, 256, 0, stream>>>(W1, W2, w1t, w2t);

    const dim3 ggrid(391, 2);                    // 391 x 128 rows x 2 halves
    const int agg_grid = (N_NODES + 3) / 4;      // 12500 per half

    // ---- layer 1 (x f32 -> fp16 + dinv-scale fused into GEMM) ----
    k_gemm_mfma<true><<<ggrid, 256, 0, stream>>>(x, nullptr, w1t, dinv, hA, N_NODES);
    k_aggregate<<<agg_grid, 256, 0, stream>>>(hA, row_start, csr, dinv, b1, hB, 0);
    k_aggregate<<<agg_grid, 256, 0, stream>>>(hA, row_start, csr, dinv, b1, hB, 1);

    // ---- layer 2 ----
    k_gemm_mfma<false><<<ggrid, 256, 0, stream>>>(nullptr, hB, w2t, dinv, hA, N_NODES);
    k_aggregate<<<agg_grid, 256, 0, stream>>>(hA, row_start, csr, dinv, b2, hB, 0);
    k_aggregate<<<agg_grid, 256, 0, stream>>>(hA, row_start, csr, dinv, b2, hB, 1);

    // ---- pooling + head ----
    hipMemsetAsync(pooled, 0, NGRAPH * NFEAT * sizeof(float), stream);
    k_pool<<<625, 256, 0, stream>>>(hB, batch, pooled);
    k_final<<<NGRAPH, 256, 0, stream>>>(pooled, Wout, bout, out);
}

// Round 16
// 264.214 us; speedup vs baseline: 1.1394x; 1.0489x over previous
//
#include <hip/hip_runtime.h>
#include <hip/hip_fp16.h>

#define N_NODES 50000
#define NFEAT   256
#define NGRAPH  64
#define NEDGE   800000
#define NBUCK   98      // ceil(50000/512) buckets of 512 nodes
#define BWIN    16384   // fixed tmp window per bucket (mean 8163, sigma~90)

typedef __attribute__((ext_vector_type(8))) _Float16 half8;
typedef __attribute__((ext_vector_type(2))) _Float16 h2v;
typedef __attribute__((ext_vector_type(4))) float f32x4;
struct alignas(8) US4 { unsigned short x, y, z, w; };

static __device__ __forceinline__ float h2f(unsigned short u) {
    return __half2float(__ushort_as_half(u));
}
static __device__ __forceinline__ unsigned short f2h(float f) {
    return __half_as_ushort(__float2half(f));
}

// ================= CSR build, phase A: bin edges into buckets =================
__global__ __launch_bounds__(256) void k_bin(const int* __restrict__ src,
                                             const int* __restrict__ dst,
                                             int* __restrict__ bcnt,
                                             unsigned int* __restrict__ tmp) {
    __shared__ int hist[NBUCK];
    __shared__ int base[NBUCK];
    const int t = threadIdx.x;
    if (t < NBUCK) hist[t] = 0;
    __syncthreads();
    const int e0 = blockIdx.x * 1024 + t * 4;
    int s[4], d[4], b[4], rk[4];
#pragma unroll
    for (int i = 0; i < 4; ++i) {
        const int e = e0 + i;
        if (e < NEDGE) {
            s[i] = src[e];
            d[i] = dst[e];
            b[i] = d[i] >> 9;
            rk[i] = atomicAdd(&hist[b[i]], 1);
        } else {
            b[i] = -1;
        }
    }
    __syncthreads();
    if (t < NBUCK) base[t] = atomicAdd(&bcnt[t], hist[t]);
    __syncthreads();
#pragma unroll
    for (int i = 0; i < 4; ++i) {
        if (b[i] >= 0)
            tmp[(size_t)b[i] * BWIN + base[b[i]] + rk[i]] =
                ((unsigned int)s[i] << 16) | (unsigned int)d[i];
    }
}

// ================= phase A.5: exclusive scan of bucket totals (1 wave) =================
__global__ void k_bscan(const int* __restrict__ bcnt, int* __restrict__ bbase) {
    const int l = threadIdx.x;  // 64 lanes, lane l owns buckets 2l, 2l+1
    const int i0 = 2 * l, i1 = 2 * l + 1;
    const int v0 = (i0 < NBUCK) ? bcnt[i0] : 0;
    const int v1 = (i1 < NBUCK) ? bcnt[i1] : 0;
    const int ps = v0 + v1;
    int incl = ps;
#pragma unroll
    for (int off = 1; off < 64; off <<= 1) {
        int u = __shfl_up(incl, off, 64);
        if (l >= off) incl += u;
    }
    const int excl = incl - ps;
    if (i0 < NBUCK) bbase[i0] = excl;
    if (i1 < NBUCK) bbase[i1] = excl + v0;
}

// ================= phase B: per-bucket local count/scan/place =================
__global__ __launch_bounds__(256) void k_build(const unsigned int* __restrict__ tmp,
                                               const int* __restrict__ bcnt,
                                               const int* __restrict__ bbase,
                                               int* __restrict__ row_start,
                                               float* __restrict__ dinv,
                                               unsigned short* __restrict__ csr) {
    __shared__ int cnt[512];
    __shared__ int cur[512];
    __shared__ int wtot[4];
    const int bk = blockIdx.x, t = threadIdx.x;
    const int node0 = bk << 9;
    const int n = bcnt[bk];
    const unsigned int* rec = tmp + (size_t)bk * BWIN;
    cnt[t] = 0;
    cnt[t + 256] = 0;
    __syncthreads();
    for (int i = t; i < n; i += 256) atomicAdd(&cnt[rec[i] & 511], 1);
    __syncthreads();
    const int lane = t & 63, w = t >> 6;
    const int v0 = cnt[2 * t], v1 = cnt[2 * t + 1];
    const int ps = v0 + v1;
    int incl = ps;
#pragma unroll
    for (int off = 1; off < 64; off <<= 1) {
        int u = __shfl_up(incl, off, 64);
        if (lane >= off) incl += u;
    }
    if (lane == 63) wtot[w] = incl;
    __syncthreads();
    int wbase = 0;
#pragma unroll
    for (int k = 0; k < 4; ++k) wbase += (k < w) ? wtot[k] : 0;
    const int excl = wbase + incl - ps;
    const int gb = bbase[bk];
    const int g0 = node0 + 2 * t;
    if (g0 < N_NODES) {
        row_start[g0] = gb + excl;
        dinv[g0] = rsqrtf((float)v0 + 1.0f);
    }
    if (g0 + 1 < N_NODES) {
        row_start[g0 + 1] = gb + excl + v0;
        dinv[g0 + 1] = rsqrtf((float)v1 + 1.0f);
    }
    cur[2 * t] = gb + excl;
    cur[2 * t + 1] = gb + excl + v0;
    __syncthreads();
    for (int i = t; i < n; i += 256) {
        const unsigned int r = rec[i];
        const int pos = atomicAdd(&cur[r & 511], 1);
        csr[pos] = (unsigned short)(r >> 16);  // src only
    }
    if (bk == 0 && t == 0) row_start[N_NODES] = NEDGE;
}

// ================= W prep: W[k][n] f32 -> Wt [n][k] fp16 =================
__global__ void k_prep_w(const float* __restrict__ W1, const float* __restrict__ W2,
                         unsigned short* __restrict__ w1t, unsigned short* __restrict__ w2t) {
    const int l = blockIdx.x >> 8;
    const int idx = (blockIdx.x & 255) * 256 + threadIdx.x;
    const int n = idx >> 8, k = idx & 255;
    const float* W = l ? W2 : W1;
    unsigned short* wt = l ? w2t : w1t;
    wt[n * 256 + k] = f2h(W[k * 256 + n]);
}

// ================= fp16 MFMA GEMM: Chs[half][node][128] = dinv .* (A @ W) ==========
// Full B-half (64KB) in LDS, ONE barrier; wave streams 32 A-rows (2 chunks).
// ks-pipelined bf prefetch (bc/bn register double-buffer) for ds_read ILP.
// launch_bounds(256,2): 8 waves/CU (LDS-capped), VGPR cap 256 -> no spill.
template <bool AF32>
__global__ __launch_bounds__(256, 2) void k_gemm_mfma(const float* __restrict__ Af,
                                                      const unsigned short* __restrict__ Ah,
                                                      const unsigned short* __restrict__ Wt,
                                                      const float* __restrict__ dinv,
                                                      unsigned short* __restrict__ Ch, int M) {
    __shared__ unsigned short lds[32768];  // [ks(8)][n(128)][32k] swizzled k-groups
    const int t = threadIdx.x;
    const int half = blockIdx.y;
    const int m0 = blockIdx.x * 128;
    const int w = t >> 6, lane = t & 63;
    const int lr = lane & 15, g = lane >> 4;

    {
        const unsigned short* wbase = Wt + (size_t)half * 128 * 256;
#pragma unroll
        for (int it = 0; it < 16; ++it) {
            const int unit = it * 256 + t;
            const int n = unit >> 5;
            const int rem = unit & 31;
            const int ks = rem >> 2, kg = rem & 3;
            const half8 v = *(const half8*)&wbase[n * 256 + rem * 8];
            const int kgx = kg ^ ((n >> 1) & 3);
            *(half8*)&lds[ks * 4096 + n * 32 + kgx * 8] = v;
        }
    }
    __syncthreads();  // the ONLY barrier

    const int rbase = m0 + w * 32;
    unsigned short* Chh = Ch + (size_t)half * (size_t)N_NODES * 128;

    // per-ni LDS element offsets (ks term is a compile-time immediate in the loop)
    int boff[8];
#pragma unroll
    for (int ni = 0; ni < 8; ++ni) {
        const int n = ni * 16 + lr;
        boff[ni] = n * 32 + ((g ^ ((n >> 1) & 3)) << 3);
    }

    half8 aA[8], aB[8];

#define LOADCHUNK(C, DST)                                                                \
    {                                                                                    \
        const int row = min(rbase + (C) * 16 + lr, M - 1);                               \
        _Pragma("unroll") for (int ks = 0; ks < 8; ++ks) {                               \
            if (AF32) {                                                                  \
                const float* ap = Af + (size_t)row * 256 + ks * 32 + g * 8;              \
                const float4 p0 = *(const float4*)ap;                                    \
                const float4 p1 = *(const float4*)(ap + 4);                              \
                half8 h;                                                                 \
                h[0] = (_Float16)p0.x; h[1] = (_Float16)p0.y;                            \
                h[2] = (_Float16)p0.z; h[3] = (_Float16)p0.w;                            \
                h[4] = (_Float16)p1.x; h[5] = (_Float16)p1.y;                            \
                h[6] = (_Float16)p1.z; h[7] = (_Float16)p1.w;                            \
                DST[ks] = h;                                                             \
            } else {                                                                     \
                DST[ks] = *(const half8*)(Ah + (size_t)(ks >> 2) * (size_t)N_NODES * 128 \
                                          + (size_t)row * 128 + (ks & 3) * 32 + g * 8);  \
            }                                                                            \
        }                                                                                \
    }

#define COMPUTE(C, SRC)                                                                  \
    {                                                                                    \
        f32x4 acc[8] = {};                                                               \
        half8 bc[8];                                                                     \
        _Pragma("unroll") for (int ni = 0; ni < 8; ++ni)                                 \
            bc[ni] = *(const half8*)&lds[boff[ni]];                                      \
        _Pragma("unroll") for (int ks = 0; ks < 8; ++ks) {                               \
            half8 bn[8];                                                                 \
            if (ks < 7) {                                                                \
                _Pragma("unroll") for (int ni = 0; ni < 8; ++ni)                         \
                    bn[ni] = *(const half8*)&lds[(ks + 1) * 4096 + boff[ni]];            \
            }                                                                            \
            _Pragma("unroll") for (int ni = 0; ni < 8; ++ni)                             \
                acc[ni] = __builtin_amdgcn_mfma_f32_16x16x32_f16(SRC[ks], bc[ni],        \
                                                                 acc[ni], 0, 0, 0);      \
            _Pragma("unroll") for (int ni = 0; ni < 8; ++ni) bc[ni] = bn[ni];            \
        }                                                                                \
        const int r0 = rbase + (C) * 16 + g * 4;                                         \
        float dv[4];                                                                     \
        _Pragma("unroll") for (int r = 0; r < 4; ++r)                                    \
            dv[r] = dinv[min(r0 + r, M - 1)];                                            \
        _Pragma("unroll") for (int ni = 0; ni < 8; ++ni) {                               \
            const int col = ni * 16 + lr;                                                \
            _Pragma("unroll") for (int r = 0; r < 4; ++r) {                              \
                if (r0 + r < M)                                                          \
                    Chh[(size_t)(r0 + r) * 128 + col] = f2h(acc[ni][r] * dv[r]);         \
            }                                                                            \
        }                                                                                \
    }

    LOADCHUNK(0, aA)
    LOADCHUNK(1, aB)
    COMPUTE(0, aA)
    COMPUTE(1, aB)

#undef LOADCHUNK
#undef COMPUTE
}

// ================= aggregation: out[d] = relu(b + dinv[d]*(hs[d] + sum hs[s])) =========
// csr = src-only ushort; weight-free fdot2; wave per (node, half), half-0 wids first.
__global__ __launch_bounds__(256) void k_aggregate(const unsigned short* __restrict__ hs,
                                                   const int* __restrict__ row_start,
                                                   const unsigned short* __restrict__ csr,
                                                   const float* __restrict__ dinv,
                                                   const float* __restrict__ bias,
                                                   unsigned short* __restrict__ out) {
    const int wid = blockIdx.x * 4 + (threadIdx.x >> 6);
    if (wid >= 2 * N_NODES) return;
    const int half = (wid >= N_NODES) ? 1 : 0;
    const int node = wid - half * N_NODES;
    const int lane = threadIdx.x & 63;
    const int sub = lane >> 4;   // 0..3: edge-pair index
    const int fl = lane & 15;    // 8 feats per lane
    const unsigned int* hu = (const unsigned int*)(hs + (size_t)half * N_NODES * 128);
    const h2v one2 = {(_Float16)1.0f, (_Float16)1.0f};

    float acc[8] = {};
    const int s0 = row_start[node], s1 = row_start[node + 1];
    const unsigned short* row = csr + s0;
    const int n = s1 - s0;

#define EDGEPAIR(VA, VB)                                                                   \
    {                                                                                      \
        unsigned int plo, phi;                                                             \
        plo = __builtin_amdgcn_perm(VB.x, VA.x, 0x05040100u);                              \
        phi = __builtin_amdgcn_perm(VB.x, VA.x, 0x07060302u);                              \
        acc[0] = __builtin_amdgcn_fdot2(__builtin_bit_cast(h2v, plo), one2, acc[0], false);\
        acc[1] = __builtin_amdgcn_fdot2(__builtin_bit_cast(h2v, phi), one2, acc[1], false);\
        plo = __builtin_amdgcn_perm(VB.y, VA.y, 0x05040100u);                              \
        phi = __builtin_amdgcn_perm(VB.y, VA.y, 0x07060302u);                              \
        acc[2] = __builtin_amdgcn_fdot2(__builtin_bit_cast(h2v, plo), one2, acc[2], false);\
        acc[3] = __builtin_amdgcn_fdot2(__builtin_bit_cast(h2v, phi), one2, acc[3], false);\
        plo = __builtin_amdgcn_perm(VB.z, VA.z, 0x05040100u);                              \
        phi = __builtin_amdgcn_perm(VB.z, VA.z, 0x07060302u);                              \
        acc[4] = __builtin_amdgcn_fdot2(__builtin_bit_cast(h2v, plo), one2, acc[4], false);\
        acc[5] = __builtin_amdgcn_fdot2(__builtin_bit_cast(h2v, phi), one2, acc[5], false);\
        plo = __builtin_amdgcn_perm(VB.w, VA.w, 0x05040100u);                              \
        phi = __builtin_amdgcn_perm(VB.w, VA.w, 0x07060302u);                              \
        acc[6] = __builtin_amdgcn_fdot2(__builtin_bit_cast(h2v, plo), one2, acc[6], false);\
        acc[7] = __builtin_amdgcn_fdot2(__builtin_bit_cast(h2v, phi), one2, acc[7], false);\
    }

    const int nfull = n & ~7;
    int j = 0;
    for (; j < nfull; j += 8) {
        const int sa = row[j + sub * 2];
        const int sb = row[j + sub * 2 + 1];
        const uint4 va = *(const uint4*)(hu + (size_t)sa * 64 + fl * 4);
        const uint4 vb = *(const uint4*)(hu + (size_t)sb * 64 + fl * 4);
        EDGEPAIR(va, vb)
    }
    if (j < n) {
        const int ia = j + sub * 2, ib = ia + 1;
        uint4 va = {0, 0, 0, 0}, vb = {0, 0, 0, 0};
        if (ia < n) va = *(const uint4*)(hu + (size_t)row[ia] * 64 + fl * 4);
        if (ib < n) vb = *(const uint4*)(hu + (size_t)row[ib] * 64 + fl * 4);
        EDGEPAIR(va, vb)
    }
#undef EDGEPAIR

#pragma unroll
    for (int i = 0; i < 8; ++i) {
        acc[i] += __shfl_xor(acc[i], 16, 64);
        acc[i] += __shfl_xor(acc[i], 32, 64);
    }

    if (sub == 0) {
        const float dd = dinv[node];
        const uint4 sh = *(const uint4*)(hu + (size_t)node * 64 + fl * 4);
        const float4 b0 = *(const float4*)(bias + half * 128 + fl * 8);
        const float4 b1 = *(const float4*)(bias + half * 128 + fl * 8 + 4);
        float r[8];
        r[0] = fmaf(acc[0] + h2f((unsigned short)(sh.x & 0xffff)), dd, b0.x);
        r[1] = fmaf(acc[1] + h2f((unsigned short)(sh.x >> 16)),    dd, b0.y);
        r[2] = fmaf(acc[2] + h2f((unsigned short)(sh.y & 0xffff)), dd, b0.z);
        r[3] = fmaf(acc[3] + h2f((unsigned short)(sh.y >> 16)),    dd, b0.w);
        r[4] = fmaf(acc[4] + h2f((unsigned short)(sh.z & 0xffff)), dd, b1.x);
        r[5] = fmaf(acc[5] + h2f((unsigned short)(sh.z >> 16)),    dd, b1.y);
        r[6] = fmaf(acc[6] + h2f((unsigned short)(sh.w & 0xffff)), dd, b1.z);
        r[7] = fmaf(acc[7] + h2f((unsigned short)(sh.w >> 16)),    dd, b1.w);
#pragma unroll
        for (int i = 0; i < 8; ++i) r[i] = fmaxf(r[i], 0.f);
        uint4 o;
        o.x = (unsigned int)f2h(r[0]) | ((unsigned int)f2h(r[1]) << 16);
        o.y = (unsigned int)f2h(r[2]) | ((unsigned int)f2h(r[3]) << 16);
        o.z = (unsigned int)f2h(r[4]) | ((unsigned int)f2h(r[5]) << 16);
        o.w = (unsigned int)f2h(r[6]) | ((unsigned int)f2h(r[7]) << 16);
        *(uint4*)((unsigned int*)(out + (size_t)half * N_NODES * 128) +
                  (size_t)node * 64 + fl * 4) = o;
    }
}

// ================= pooling (batch sorted) + head =================
__global__ void k_pool(const unsigned short* __restrict__ h2, const int* __restrict__ batch,
                       float* __restrict__ pooled) {
    const int strip = blockIdx.x * 2 + (threadIdx.x >> 7);
    const int tf = threadIdx.x & 127;
    const int f = tf * 2;
    const unsigned short* base = h2 + (size_t)(f >> 7) * N_NODES * 128 + (f & 127);
    const int n0 = strip * 40, n1 = n0 + 40;
    int g = batch[n0];
    float ax = 0.f, ay = 0.f;
    for (int n = n0; n < n1; ++n) {
        const int bg = batch[n];
        if (bg != g) {
            unsafeAtomicAdd(&pooled[g * NFEAT + f], ax);
            unsafeAtomicAdd(&pooled[g * NFEAT + f + 1], ay);
            ax = ay = 0.f;
            g = bg;
        }
        const unsigned int u = *(const unsigned int*)(base + (size_t)n * 128);
        ax += h2f((unsigned short)(u & 0xffff));
        ay += h2f((unsigned short)(u >> 16));
    }
    unsafeAtomicAdd(&pooled[g * NFEAT + f], ax);
    unsafeAtomicAdd(&pooled[g * NFEAT + f + 1], ay);
}

__global__ void k_final(const float* __restrict__ pooled, const float* __restrict__ Wout,
                        const float* __restrict__ bout, float* __restrict__ out) {
    const int g = blockIdx.x, t = threadIdx.x;
    float v = pooled[g * NFEAT + t] * Wout[t];
#pragma unroll
    for (int off = 32; off > 0; off >>= 1) v += __shfl_down(v, off, 64);
    __shared__ float sred[4];
    if ((t & 63) == 0) sred[t >> 6] = v;
    __syncthreads();
    if (t == 0) out[g] = sred[0] + sred[1] + sred[2] + sred[3] + bout[0];
}

extern "C" void kernel_launch(void* const* d_in, const int* in_sizes, int n_in,
                              void* d_out, int out_size, void* d_ws, size_t ws_size,
                              hipStream_t stream) {
    const float* x     = (const float*)d_in[0];
    const int*   ei    = (const int*)d_in[1];
    const int*   batch = (const int*)d_in[2];
    const float* W1    = (const float*)d_in[3];
    const float* b1    = (const float*)d_in[4];
    const float* W2    = (const float*)d_in[5];
    const float* b2    = (const float*)d_in[6];
    const float* Wout  = (const float*)d_in[7];
    const float* bout  = (const float*)d_in[8];
    float* out = (float*)d_out;

    const int* srcp = ei;
    const int* dstp = ei + NEDGE;

    const size_t NE128 = (size_t)N_NODES * 128;  // elements per half-plane
    unsigned short* hA = (unsigned short*)d_ws;            // [2][N][128] fp16 (dinv-scaled)
    unsigned short* hB = hA + 2 * NE128;                   // [2][N][128] fp16
    float* dinv      = (float*)(hB + 2 * NE128);           // 50000
    float* pooled    = dinv + N_NODES;                     // 16384
    int*   row_start = (int*)(pooled + NGRAPH * NFEAT);    // 50001 (+pad)
    int*   bcnt      = row_start + N_NODES + 3;            // 98
    int*   bbase     = bcnt + NBUCK;                       // 98
    unsigned short* csr = (unsigned short*)(bbase + NBUCK);// 800000 ushort
    unsigned int* tmp = (unsigned int*)(csr + NEDGE);      // 98*16384 uint
    unsigned short* w1t = (unsigned short*)(tmp + (size_t)NBUCK * BWIN);  // 65536 each
    unsigned short* w2t = w1t + 65536;

    // ---- CSR build: bucketed two-phase ----
    hipMemsetAsync(bcnt, 0, NBUCK * sizeof(int), stream);
    k_bin<<<(NEDGE + 1023) / 1024, 256, 0, stream>>>(srcp, dstp, bcnt, tmp);
    k_bscan<<<1, 64, 0, stream>>>(bcnt, bbase);
    k_build<<<NBUCK, 256, 0, stream>>>(tmp, bcnt, bbase, row_start, dinv, csr);

    // ---- weight prep ----
    k_prep_w<<<512, 256, 0, stream>>>(W1, W2, w1t, w2t);

    const dim3 ggrid(391, 2);                    // 391 x 128 rows x 2 halves
    const int agg_grid = (2 * N_NODES + 3) / 4;  // 25000

    // ---- layer 1 (x f32 -> fp16 + dinv-scale fused into GEMM) ----
    k_gemm_mfma<true><<<ggrid, 256, 0, stream>>>(x, nullptr, w1t, dinv, hA, N_NODES);
    k_aggregate<<<agg_grid, 256, 0, stream>>>(hA, row_start, csr, dinv, b1, hB);

    // ---- layer 2 ----
    k_gemm_mfma<false><<<ggrid, 256, 0, stream>>>(nullptr, hB, w2t, dinv, hA, N_NODES);
    k_aggregate<<<agg_grid, 256, 0, stream>>>(hA, row_start, csr, dinv, b2, hB);

    // ---- pooling + head ----
    hipMemsetAsync(pooled, 0, NGRAPH * NFEAT * sizeof(float), stream);
    k_pool<<<625, 256, 0, stream>>>(hB, batch, pooled);
    k_final<<<NGRAPH, 256, 0, stream>>>(pooled, Wout, bout, out);
}

// Round 17
// 255.754 us; speedup vs baseline: 1.1771x; 1.0331x over previous
//
#include <hip/hip_runtime.h>
#include <hip/hip_fp16.h>

#define N_NODES 50000
#define NFEAT   256
#define NGRAPH  64
#define NEDGE   800000
#define NBUCK   98      // ceil(50000/512) buckets of 512 nodes
#define BWIN    16384   // fixed tmp window per bucket (mean 8163, sigma~90)

typedef __attribute__((ext_vector_type(8))) _Float16 half8;
typedef __attribute__((ext_vector_type(2))) _Float16 h2v;
typedef __attribute__((ext_vector_type(4))) float f32x4;
struct alignas(8) US4 { unsigned short x, y, z, w; };

static __device__ __forceinline__ float h2f(unsigned short u) {
    return __half2float(__ushort_as_half(u));
}
static __device__ __forceinline__ unsigned short f2h(float f) {
    return __half_as_ushort(__float2half(f));
}

// ================= CSR build, phase A: bin edges into buckets =================
__global__ __launch_bounds__(256) void k_bin(const int* __restrict__ src,
                                             const int* __restrict__ dst,
                                             int* __restrict__ bcnt,
                                             unsigned int* __restrict__ tmp) {
    __shared__ int hist[NBUCK];
    __shared__ int base[NBUCK];
    const int t = threadIdx.x;
    if (t < NBUCK) hist[t] = 0;
    __syncthreads();
    const int e0 = blockIdx.x * 1024 + t * 4;
    int s[4], d[4], b[4], rk[4];
#pragma unroll
    for (int i = 0; i < 4; ++i) {
        const int e = e0 + i;
        if (e < NEDGE) {
            s[i] = src[e];
            d[i] = dst[e];
            b[i] = d[i] >> 9;
            rk[i] = atomicAdd(&hist[b[i]], 1);
        } else {
            b[i] = -1;
        }
    }
    __syncthreads();
    if (t < NBUCK) base[t] = atomicAdd(&bcnt[t], hist[t]);
    __syncthreads();
#pragma unroll
    for (int i = 0; i < 4; ++i) {
        if (b[i] >= 0)
            tmp[(size_t)b[i] * BWIN + base[b[i]] + rk[i]] =
                ((unsigned int)s[i] << 16) | (unsigned int)d[i];
    }
}

// ================= phase A.5: exclusive scan of bucket totals (1 wave) =================
__global__ void k_bscan(const int* __restrict__ bcnt, int* __restrict__ bbase) {
    const int l = threadIdx.x;
    const int i0 = 2 * l, i1 = 2 * l + 1;
    const int v0 = (i0 < NBUCK) ? bcnt[i0] : 0;
    const int v1 = (i1 < NBUCK) ? bcnt[i1] : 0;
    const int ps = v0 + v1;
    int incl = ps;
#pragma unroll
    for (int off = 1; off < 64; off <<= 1) {
        int u = __shfl_up(incl, off, 64);
        if (l >= off) incl += u;
    }
    const int excl = incl - ps;
    if (i0 < NBUCK) bbase[i0] = excl;
    if (i1 < NBUCK) bbase[i1] = excl + v0;
}

// ================= phase B: per-bucket local count/scan/place =================
__global__ __launch_bounds__(256) void k_build(const unsigned int* __restrict__ tmp,
                                               const int* __restrict__ bcnt,
                                               const int* __restrict__ bbase,
                                               int* __restrict__ row_start,
                                               float* __restrict__ dinv,
                                               unsigned short* __restrict__ csr) {
    __shared__ int cnt[512];
    __shared__ int cur[512];
    __shared__ int wtot[4];
    const int bk = blockIdx.x, t = threadIdx.x;
    const int node0 = bk << 9;
    const int n = bcnt[bk];
    const unsigned int* rec = tmp + (size_t)bk * BWIN;
    cnt[t] = 0;
    cnt[t + 256] = 0;
    __syncthreads();
    for (int i = t; i < n; i += 256) atomicAdd(&cnt[rec[i] & 511], 1);
    __syncthreads();
    const int lane = t & 63, w = t >> 6;
    const int v0 = cnt[2 * t], v1 = cnt[2 * t + 1];
    const int ps = v0 + v1;
    int incl = ps;
#pragma unroll
    for (int off = 1; off < 64; off <<= 1) {
        int u = __shfl_up(incl, off, 64);
        if (lane >= off) incl += u;
    }
    if (lane == 63) wtot[w] = incl;
    __syncthreads();
    int wbase = 0;
#pragma unroll
    for (int k = 0; k < 4; ++k) wbase += (k < w) ? wtot[k] : 0;
    const int excl = wbase + incl - ps;
    const int gb = bbase[bk];
    const int g0 = node0 + 2 * t;
    if (g0 < N_NODES) {
        row_start[g0] = gb + excl;
        dinv[g0] = rsqrtf((float)v0 + 1.0f);
    }
    if (g0 + 1 < N_NODES) {
        row_start[g0 + 1] = gb + excl + v0;
        dinv[g0 + 1] = rsqrtf((float)v1 + 1.0f);
    }
    cur[2 * t] = gb + excl;
    cur[2 * t + 1] = gb + excl + v0;
    __syncthreads();
    for (int i = t; i < n; i += 256) {
        const unsigned int r = rec[i];
        const int pos = atomicAdd(&cur[r & 511], 1);
        csr[pos] = (unsigned short)(r >> 16);  // src only
    }
    if (bk == 0 && t == 0) row_start[N_NODES] = NEDGE;
}

// ================= W prep: W[k][n] f32 -> Wt [n][k] fp16 =================
__global__ void k_prep_w(const float* __restrict__ W1, const float* __restrict__ W2,
                         unsigned short* __restrict__ w1t, unsigned short* __restrict__ w2t) {
    const int l = blockIdx.x >> 8;
    const int idx = (blockIdx.x & 255) * 256 + threadIdx.x;
    const int n = idx >> 8, k = idx & 255;
    const float* W = l ? W2 : W1;
    unsigned short* wt = l ? w2t : w1t;
    wt[n * 256 + k] = f2h(W[k * 256 + n]);
}

// ================= fp16 MFMA GEMM: Chs[half][node][128] = dinv .* (A @ W) ==========
// Full B-half (64KB) in LDS, ONE barrier; wave streams 32 A-rows (2 chunks).
// ks-pipelined bf prefetch; SWAPPED-operand MFMA -> lane holds (row=lr, 4 consec
// cols) -> 8 packed 8B C-stores + single dinv[row] load per lane per chunk.
template <bool AF32>
__global__ __launch_bounds__(256, 2) void k_gemm_mfma(const float* __restrict__ Af,
                                                      const unsigned short* __restrict__ Ah,
                                                      const unsigned short* __restrict__ Wt,
                                                      const float* __restrict__ dinv,
                                                      unsigned short* __restrict__ Ch, int M) {
    __shared__ unsigned short lds[32768];  // [ks(8)][n(128)][32k] swizzled k-groups
    const int t = threadIdx.x;
    const int half = blockIdx.y;
    const int m0 = blockIdx.x * 128;
    const int w = t >> 6, lane = t & 63;
    const int lr = lane & 15, g = lane >> 4;

    {
        const unsigned short* wbase = Wt + (size_t)half * 128 * 256;
#pragma unroll
        for (int it = 0; it < 16; ++it) {
            const int unit = it * 256 + t;
            const int n = unit >> 5;
            const int rem = unit & 31;
            const int ks = rem >> 2, kg = rem & 3;
            const half8 v = *(const half8*)&wbase[n * 256 + rem * 8];
            const int kgx = kg ^ ((n >> 1) & 3);
            *(half8*)&lds[ks * 4096 + n * 32 + kgx * 8] = v;
        }
    }
    __syncthreads();  // the ONLY barrier

    const int rbase = m0 + w * 32;
    unsigned short* Chh = Ch + (size_t)half * (size_t)N_NODES * 128;

    int boff[8];
#pragma unroll
    for (int ni = 0; ni < 8; ++ni) {
        const int n = ni * 16 + lr;
        boff[ni] = n * 32 + ((g ^ ((n >> 1) & 3)) << 3);
    }

    half8 aA[8], aB[8];

#define LOADCHUNK(C, DST)                                                                \
    {                                                                                    \
        const int row = min(rbase + (C) * 16 + lr, M - 1);                               \
        _Pragma("unroll") for (int ks = 0; ks < 8; ++ks) {                               \
            if (AF32) {                                                                  \
                const float* ap = Af + (size_t)row * 256 + ks * 32 + g * 8;              \
                const float4 p0 = *(const float4*)ap;                                    \
                const float4 p1 = *(const float4*)(ap + 4);                              \
                half8 h;                                                                 \
                h[0] = (_Float16)p0.x; h[1] = (_Float16)p0.y;                            \
                h[2] = (_Float16)p0.z; h[3] = (_Float16)p0.w;                            \
                h[4] = (_Float16)p1.x; h[5] = (_Float16)p1.y;                            \
                h[6] = (_Float16)p1.z; h[7] = (_Float16)p1.w;                            \
                DST[ks] = h;                                                             \
            } else {                                                                     \
                DST[ks] = *(const half8*)(Ah + (size_t)(ks >> 2) * (size_t)N_NODES * 128 \
                                          + (size_t)row * 128 + (ks & 3) * 32 + g * 8);  \
            }                                                                            \
        }                                                                                \
    }

// swapped operands: D = mfma(bf, af) = C^T fragment; lane: row = rbase+C*16+lr,
// cols = ni*16 + g*4 + [0..3]  -> packed 8B stores, one dinv[row] per lane.
#define COMPUTE(C, SRC)                                                                  \
    {                                                                                    \
        f32x4 acc[8] = {};                                                               \
        half8 bc[8];                                                                     \
        _Pragma("unroll") for (int ni = 0; ni < 8; ++ni)                                 \
            bc[ni] = *(const half8*)&lds[boff[ni]];                                      \
        _Pragma("unroll") for (int ks = 0; ks < 8; ++ks) {                               \
            half8 bn[8];                                                                 \
            if (ks < 7) {                                                                \
                _Pragma("unroll") for (int ni = 0; ni < 8; ++ni)                         \
                    bn[ni] = *(const half8*)&lds[(ks + 1) * 4096 + boff[ni]];            \
            }                                                                            \
            _Pragma("unroll") for (int ni = 0; ni < 8; ++ni)                             \
                acc[ni] = __builtin_amdgcn_mfma_f32_16x16x32_f16(bc[ni], SRC[ks],        \
                                                                 acc[ni], 0, 0, 0);      \
            _Pragma("unroll") for (int ni = 0; ni < 8; ++ni) bc[ni] = bn[ni];            \
        }                                                                                \
        const int row = rbase + (C) * 16 + lr;                                           \
        const float dv = dinv[min(row, M - 1)];                                          \
        if (row < M) {                                                                   \
            _Pragma("unroll") for (int ni = 0; ni < 8; ++ni) {                           \
                US4 o;                                                                   \
                o.x = f2h(acc[ni][0] * dv); o.y = f2h(acc[ni][1] * dv);                  \
                o.z = f2h(acc[ni][2] * dv); o.w = f2h(acc[ni][3] * dv);                  \
                *(US4*)(Chh + (size_t)row * 128 + ni * 16 + g * 4) = o;                  \
            }                                                                            \
        }                                                                                \
    }

    LOADCHUNK(0, aA)
    LOADCHUNK(1, aB)
    COMPUTE(0, aA)
    COMPUTE(1, aB)

#undef LOADCHUNK
#undef COMPUTE
}

// ================= aggregation: out[d] = relu(b + dinv[d]*(hs[d] + sum hs[s])) =========
// csr = src-only ushort; pairwise v_pk_add_f16 + fdot2-unpack (12 VALU/edge-pair).
__global__ __launch_bounds__(256) void k_aggregate(const unsigned short* __restrict__ hs,
                                                   const int* __restrict__ row_start,
                                                   const unsigned short* __restrict__ csr,
                                                   const float* __restrict__ dinv,
                                                   const float* __restrict__ bias,
                                                   unsigned short* __restrict__ out) {
    const int wid = blockIdx.x * 4 + (threadIdx.x >> 6);
    if (wid >= 2 * N_NODES) return;
    const int half = (wid >= N_NODES) ? 1 : 0;
    const int node = wid - half * N_NODES;
    const int lane = threadIdx.x & 63;
    const int sub = lane >> 4;   // 0..3: edge-pair index
    const int fl = lane & 15;    // 8 feats per lane
    const unsigned int* hu = (const unsigned int*)(hs + (size_t)half * N_NODES * 128);
    const h2v e0v = {(_Float16)1.0f, (_Float16)0.0f};
    const h2v e1v = {(_Float16)0.0f, (_Float16)1.0f};

    float acc[8] = {};
    const int s0 = row_start[node], s1 = row_start[node + 1];
    const unsigned short* row = csr + s0;
    const int n = s1 - s0;

#define EDGEPAIR(VA, VB)                                                                   \
    {                                                                                      \
        h2v s;                                                                             \
        s = __builtin_bit_cast(h2v, VA.x) + __builtin_bit_cast(h2v, VB.x);                 \
        acc[0] = __builtin_amdgcn_fdot2(s, e0v, acc[0], false);                            \
        acc[1] = __builtin_amdgcn_fdot2(s, e1v, acc[1], false);                            \
        s = __builtin_bit_cast(h2v, VA.y) + __builtin_bit_cast(h2v, VB.y);                 \
        acc[2] = __builtin_amdgcn_fdot2(s, e0v, acc[2], false);                            \
        acc[3] = __builtin_amdgcn_fdot2(s, e1v, acc[3], false);                            \
        s = __builtin_bit_cast(h2v, VA.z) + __builtin_bit_cast(h2v, VB.z);                 \
        acc[4] = __builtin_amdgcn_fdot2(s, e0v, acc[4], false);                            \
        acc[5] = __builtin_amdgcn_fdot2(s, e1v, acc[5], false);                            \
        s = __builtin_bit_cast(h2v, VA.w) + __builtin_bit_cast(h2v, VB.w);                 \
        acc[6] = __builtin_amdgcn_fdot2(s, e0v, acc[6], false);                            \
        acc[7] = __builtin_amdgcn_fdot2(s, e1v, acc[7], false);                            \
    }

    const int nfull = n & ~7;
    int j = 0;
    for (; j < nfull; j += 8) {
        const int sa = row[j + sub * 2];
        const int sb = row[j + sub * 2 + 1];
        const uint4 va = *(const uint4*)(hu + (size_t)sa * 64 + fl * 4);
        const uint4 vb = *(const uint4*)(hu + (size_t)sb * 64 + fl * 4);
        EDGEPAIR(va, vb)
    }
    if (j < n) {
        const int ia = j + sub * 2, ib = ia + 1;
        uint4 va = {0, 0, 0, 0}, vb = {0, 0, 0, 0};
        if (ia < n) va = *(const uint4*)(hu + (size_t)row[ia] * 64 + fl * 4);
        if (ib < n) vb = *(const uint4*)(hu + (size_t)row[ib] * 64 + fl * 4);
        EDGEPAIR(va, vb)
    }
#undef EDGEPAIR

#pragma unroll
    for (int i = 0; i < 8; ++i) {
        acc[i] += __shfl_xor(acc[i], 16, 64);
        acc[i] += __shfl_xor(acc[i], 32, 64);
    }

    if (sub == 0) {
        const float dd = dinv[node];
        const uint4 sh = *(const uint4*)(hu + (size_t)node * 64 + fl * 4);
        const float4 b0 = *(const float4*)(bias + half * 128 + fl * 8);
        const float4 b1 = *(const float4*)(bias + half * 128 + fl * 8 + 4);
        float r[8];
        r[0] = fmaf(acc[0] + h2f((unsigned short)(sh.x & 0xffff)), dd, b0.x);
        r[1] = fmaf(acc[1] + h2f((unsigned short)(sh.x >> 16)),    dd, b0.y);
        r[2] = fmaf(acc[2] + h2f((unsigned short)(sh.y & 0xffff)), dd, b0.z);
        r[3] = fmaf(acc[3] + h2f((unsigned short)(sh.y >> 16)),    dd, b0.w);
        r[4] = fmaf(acc[4] + h2f((unsigned short)(sh.z & 0xffff)), dd, b1.x);
        r[5] = fmaf(acc[5] + h2f((unsigned short)(sh.z >> 16)),    dd, b1.y);
        r[6] = fmaf(acc[6] + h2f((unsigned short)(sh.w & 0xffff)), dd, b1.z);
        r[7] = fmaf(acc[7] + h2f((unsigned short)(sh.w >> 16)),    dd, b1.w);
#pragma unroll
        for (int i = 0; i < 8; ++i) r[i] = fmaxf(r[i], 0.f);
        uint4 o;
        o.x = (unsigned int)f2h(r[0]) | ((unsigned int)f2h(r[1]) << 16);
        o.y = (unsigned int)f2h(r[2]) | ((unsigned int)f2h(r[3]) << 16);
        o.z = (unsigned int)f2h(r[4]) | ((unsigned int)f2h(r[5]) << 16);
        o.w = (unsigned int)f2h(r[6]) | ((unsigned int)f2h(r[7]) << 16);
        *(uint4*)((unsigned int*)(out + (size_t)half * N_NODES * 128) +
                  (size_t)node * 64 + fl * 4) = o;
    }
}

// ================= pooling (batch sorted) + head =================
__global__ void k_pool(const unsigned short* __restrict__ h2, const int* __restrict__ batch,
                       float* __restrict__ pooled) {
    const int strip = blockIdx.x * 2 + (threadIdx.x >> 7);
    const int tf = threadIdx.x & 127;
    const int f = tf * 2;
    const unsigned short* base = h2 + (size_t)(f >> 7) * N_NODES * 128 + (f & 127);
    const int n0 = strip * 40, n1 = n0 + 40;
    int g = batch[n0];
    float ax = 0.f, ay = 0.f;
    for (int n = n0; n < n1; ++n) {
        const int bg = batch[n];
        if (bg != g) {
            unsafeAtomicAdd(&pooled[g * NFEAT + f], ax);
            unsafeAtomicAdd(&pooled[g * NFEAT + f + 1], ay);
            ax = ay = 0.f;
            g = bg;
        }
        const unsigned int u = *(const unsigned int*)(base + (size_t)n * 128);
        ax += h2f((unsigned short)(u & 0xffff));
        ay += h2f((unsigned short)(u >> 16));
    }
    unsafeAtomicAdd(&pooled[g * NFEAT + f], ax);
    unsafeAtomicAdd(&pooled[g * NFEAT + f + 1], ay);
}

__global__ void k_final(const float* __restrict__ pooled, const float* __restrict__ Wout,
                        const float* __restrict__ bout, float* __restrict__ out) {
    const int g = blockIdx.x, t = threadIdx.x;
    float v = pooled[g * NFEAT + t] * Wout[t];
#pragma unroll
    for (int off = 32; off > 0; off >>= 1) v += __shfl_down(v, off, 64);
    __shared__ float sred[4];
    if ((t & 63) == 0) sred[t >> 6] = v;
    __syncthreads();
    if (t == 0) out[g] = sred[0] + sred[1] + sred[2] + sred[3] + bout[0];
}

extern "C" void kernel_launch(void* const* d_in, const int* in_sizes, int n_in,
                              void* d_out, int out_size, void* d_ws, size_t ws_size,
                              hipStream_t stream) {
    const float* x     = (const float*)d_in[0];
    const int*   ei    = (const int*)d_in[1];
    const int*   batch = (const int*)d_in[2];
    const float* W1    = (const float*)d_in[3];
    const float* b1    = (const float*)d_in[4];
    const float* W2    = (const float*)d_in[5];
    const float* b2    = (const float*)d_in[6];
    const float* Wout  = (const float*)d_in[7];
    const float* bout  = (const float*)d_in[8];
    float* out = (float*)d_out;

    const int* srcp = ei;
    const int* dstp = ei + NEDGE;

    const size_t NE128 = (size_t)N_NODES * 128;
    unsigned short* hA = (unsigned short*)d_ws;            // [2][N][128] fp16 (dinv-scaled)
    unsigned short* hB = hA + 2 * NE128;                   // [2][N][128] fp16
    float* dinv      = (float*)(hB + 2 * NE128);           // 50000
    float* pooled    = dinv + N_NODES;                     // 16384
    int*   row_start = (int*)(pooled + NGRAPH * NFEAT);    // 50001 (+pad)
    int*   bcnt      = row_start + N_NODES + 3;            // 98
    int*   bbase     = bcnt + NBUCK;                       // 98
    unsigned short* csr = (unsigned short*)(bbase + NBUCK);// 800000 ushort
    unsigned int* tmp = (unsigned int*)(csr + NEDGE);      // 98*16384 uint
    unsigned short* w1t = (unsigned short*)(tmp + (size_t)NBUCK * BWIN);  // 65536 each
    unsigned short* w2t = w1t + 65536;

    // ---- CSR build: bucketed two-phase ----
    hipMemsetAsync(bcnt, 0, NBUCK * sizeof(int), stream);
    k_bin<<<(NEDGE + 1023) / 1024, 256, 0, stream>>>(srcp, dstp, bcnt, tmp);
    k_bscan<<<1, 64, 0, stream>>>(bcnt, bbase);
    k_build<<<NBUCK, 256, 0, stream>>>(tmp, bcnt, bbase, row_start, dinv, csr);

    // ---- weight prep ----
    k_prep_w<<<512, 256, 0, stream>>>(W1, W2, w1t, w2t);

    const dim3 ggrid(391, 2);                    // 391 x 128 rows x 2 halves
    const int agg_grid = (2 * N_NODES + 3) / 4;  // 25000

    // ---- layer 1 (x f32 -> fp16 + dinv-scale fused into GEMM) ----
    k_gemm_mfma<true><<<ggrid, 256, 0, stream>>>(x, nullptr, w1t, dinv, hA, N_NODES);
    k_aggregate<<<agg_grid, 256, 0, stream>>>(hA, row_start, csr, dinv, b1, hB);

    // ---- layer 2 ----
    k_gemm_mfma<false><<<ggrid, 256, 0, stream>>>(nullptr, hB, w2t, dinv, hA, N_NODES);
    k_aggregate<<<agg_grid, 256, 0, stream>>>(hA, row_start, csr, dinv, b2, hB);

    // ---- pooling + head ----
    hipMemsetAsync(pooled, 0, NGRAPH * NFEAT * sizeof(float), stream);
    k_pool<<<625, 256, 0, stream>>>(hB, batch, pooled);
    k_final<<<NGRAPH, 256, 0, stream>>>(pooled, Wout, bout, out);
}

// Round 18
// 252.338 us; speedup vs baseline: 1.1930x; 1.0135x over previous
//
#include <hip/hip_runtime.h>
#include <hip/hip_fp16.h>

#define N_NODES 50000
#define NFEAT   256
#define NGRAPH  64
#define NEDGE   800000
#define NBUCK   98      // ceil(50000/512) buckets of 512 nodes
#define BWIN    16384   // fixed tmp window per bucket

typedef __attribute__((ext_vector_type(8))) _Float16 half8;
typedef __attribute__((ext_vector_type(2))) _Float16 h2v;
typedef __attribute__((ext_vector_type(4))) float f32x4;
struct alignas(8) US4 { unsigned short x, y, z, w; };

static __device__ __forceinline__ float h2f(unsigned short u) {
    return __half2float(__ushort_as_half(u));
}
static __device__ __forceinline__ unsigned short f2h(float f) {
    return __half_as_ushort(__float2half(f));
}

// ================= W prep (runs FIRST; also zeroes bcnt + pooled) =================
__global__ void k_prep_w(const float* __restrict__ W1, const float* __restrict__ W2,
                         unsigned short* __restrict__ w1t, unsigned short* __restrict__ w2t,
                         int* __restrict__ bcnt, float* __restrict__ pooled) {
    const int l = blockIdx.x >> 8;
    const int idx = (blockIdx.x & 255) * 256 + threadIdx.x;
    const int n = idx >> 8, k = idx & 255;
    const float* W = l ? W2 : W1;
    unsigned short* wt = l ? w2t : w1t;
    wt[n * 256 + k] = f2h(W[k * 256 + n]);
    if (l == 0) {
        if (blockIdx.x == 0 && threadIdx.x < NBUCK) bcnt[threadIdx.x] = 0;
        if (blockIdx.x >= 1 && blockIdx.x <= 64) {
            const int p = (blockIdx.x - 1) * 256 + threadIdx.x;
            if (p < NGRAPH * NFEAT) pooled[p] = 0.f;
        }
    }
}

// ================= CSR build, phase A: bin edges into buckets =================
__global__ __launch_bounds__(256) void k_bin(const int* __restrict__ src,
                                             const int* __restrict__ dst,
                                             int* __restrict__ bcnt,
                                             unsigned int* __restrict__ tmp) {
    __shared__ int hist[NBUCK];
    __shared__ int base[NBUCK];
    const int t = threadIdx.x;
    if (t < NBUCK) hist[t] = 0;
    __syncthreads();
    const int e0 = blockIdx.x * 1024 + t * 4;
    int s[4], d[4], b[4], rk[4];
#pragma unroll
    for (int i = 0; i < 4; ++i) {
        const int e = e0 + i;
        if (e < NEDGE) {
            s[i] = src[e];
            d[i] = dst[e];
            b[i] = d[i] >> 9;
            rk[i] = atomicAdd(&hist[b[i]], 1);
        } else {
            b[i] = -1;
        }
    }
    __syncthreads();
    if (t < NBUCK) base[t] = atomicAdd(&bcnt[t], hist[t]);
    __syncthreads();
#pragma unroll
    for (int i = 0; i < 4; ++i) {
        if (b[i] >= 0)
            tmp[(size_t)b[i] * BWIN + base[b[i]] + rk[i]] =
                ((unsigned int)s[i] << 16) | (unsigned int)d[i];
    }
}

// ================= phase B: per-bucket count/scan/place (+inline bucket prefix) ========
__global__ __launch_bounds__(256) void k_build(const unsigned int* __restrict__ tmp,
                                               const int* __restrict__ bcnt,
                                               int* __restrict__ row_start,
                                               float* __restrict__ dinv,
                                               unsigned short* __restrict__ csr) {
    __shared__ int cnt[512];
    __shared__ int cur[512];
    __shared__ int wtot[4];
    __shared__ int s_gb;
    const int bk = blockIdx.x, t = threadIdx.x;
    const int node0 = bk << 9;
    const int n = bcnt[bk];
    const unsigned int* rec = tmp + (size_t)bk * BWIN;
    cnt[t] = 0;
    cnt[t + 256] = 0;
    // wave 0 computes global base = sum bcnt[0..bk)
    if (t < 64) {
        int part = 0;
        for (int i = t; i < bk; i += 64) part += bcnt[i];
#pragma unroll
        for (int off = 32; off; off >>= 1) part += __shfl_down(part, off, 64);
        if (t == 0) s_gb = part;
    }
    __syncthreads();
    for (int i = t; i < n; i += 256) atomicAdd(&cnt[rec[i] & 511], 1);
    __syncthreads();
    const int lane = t & 63, w = t >> 6;
    const int v0 = cnt[2 * t], v1 = cnt[2 * t + 1];
    const int ps = v0 + v1;
    int incl = ps;
#pragma unroll
    for (int off = 1; off < 64; off <<= 1) {
        int u = __shfl_up(incl, off, 64);
        if (lane >= off) incl += u;
    }
    if (lane == 63) wtot[w] = incl;
    __syncthreads();
    int wbase = 0;
#pragma unroll
    for (int k = 0; k < 4; ++k) wbase += (k < w) ? wtot[k] : 0;
    const int excl = wbase + incl - ps;
    const int gb = s_gb;
    const int g0 = node0 + 2 * t;
    if (g0 < N_NODES) {
        row_start[g0] = gb + excl;
        dinv[g0] = rsqrtf((float)v0 + 1.0f);
    }
    if (g0 + 1 < N_NODES) {
        row_start[g0 + 1] = gb + excl + v0;
        dinv[g0 + 1] = rsqrtf((float)v1 + 1.0f);
    }
    cur[2 * t] = gb + excl;
    cur[2 * t + 1] = gb + excl + v0;
    __syncthreads();
    for (int i = t; i < n; i += 256) {
        const unsigned int r = rec[i];
        const int pos = atomicAdd(&cur[r & 511], 1);
        csr[pos] = (unsigned short)(r >> 16);  // src only
    }
    if (bk == 0 && t == 0) row_start[N_NODES] = NEDGE;
}

// ================= fp16 MFMA GEMM: Chs[half][node][128] = dinv .* (A @ W) ==========
// A-READ-ONCE: block stages W-half-0 (64KB LDS), loads 32 A-rows/wave into regs,
// computes plane 0; re-stages W-half-1 into same LDS; computes plane 1 from the
// still-live A registers. 3 barriers total; ks-pipelined ds_reads; swapped-operand
// MFMA epilogue (packed 8B stores, one dinv/lane).
template <bool AF32>
__global__ __launch_bounds__(256) void k_gemm_mfma(const float* __restrict__ Af,
                                                   const unsigned short* __restrict__ Ah,
                                                   const unsigned short* __restrict__ Wt,
                                                   const float* __restrict__ dinv,
                                                   unsigned short* __restrict__ Ch, int M) {
    __shared__ unsigned short lds[32768];  // [ks(8)][n(128)][32k], one W-half at a time
    const int t = threadIdx.x;
    const int m0 = blockIdx.x * 128;
    const int w = t >> 6, lane = t & 63;
    const int lr = lane & 15, g = lane >> 4;

    int boff[8];
#pragma unroll
    for (int ni = 0; ni < 8; ++ni) {
        const int n = ni * 16 + lr;
        boff[ni] = n * 32 + ((g ^ ((n >> 1) & 3)) << 3);
    }

    const int rbase = m0 + w * 32;
    half8 aA[8], aB[8];

#define STAGE(H)                                                                         \
    {                                                                                    \
        const unsigned short* wbase = Wt + (size_t)(H) * 128 * 256;                      \
        _Pragma("unroll") for (int it = 0; it < 16; ++it) {                              \
            const int unit = it * 256 + t;                                               \
            const int n = unit >> 5;                                                     \
            const int rem = unit & 31;                                                   \
            const int ks = rem >> 2, kg = rem & 3;                                       \
            const half8 v = *(const half8*)&wbase[n * 256 + rem * 8];                    \
            const int kgx = kg ^ ((n >> 1) & 3);                                         \
            *(half8*)&lds[ks * 4096 + n * 32 + kgx * 8] = v;                             \
        }                                                                                \
    }

#define LOADCHUNK(C, DST)                                                                \
    {                                                                                    \
        const int row = min(rbase + (C) * 16 + lr, M - 1);                               \
        _Pragma("unroll") for (int ks = 0; ks < 8; ++ks) {                               \
            if (AF32) {                                                                  \
                const float* ap = Af + (size_t)row * 256 + ks * 32 + g * 8;              \
                const float4 p0 = *(const float4*)ap;                                    \
                const float4 p1 = *(const float4*)(ap + 4);                              \
                half8 h;                                                                 \
                h[0] = (_Float16)p0.x; h[1] = (_Float16)p0.y;                            \
                h[2] = (_Float16)p0.z; h[3] = (_Float16)p0.w;                            \
                h[4] = (_Float16)p1.x; h[5] = (_Float16)p1.y;                            \
                h[6] = (_Float16)p1.z; h[7] = (_Float16)p1.w;                            \
                DST[ks] = h;                                                             \
            } else {                                                                     \
                DST[ks] = *(const half8*)(Ah + (size_t)(ks >> 2) * (size_t)N_NODES * 128 \
                                          + (size_t)row * 128 + (ks & 3) * 32 + g * 8);  \
            }                                                                            \
        }                                                                                \
    }

// swapped operands: lane holds (row = rbase+C*16+lr, cols = ni*16+g*4+[0..3])
#define COMPUTE(C, SRC, H)                                                               \
    {                                                                                    \
        unsigned short* Chh = Ch + (size_t)(H) * (size_t)N_NODES * 128;                  \
        f32x4 acc[8] = {};                                                               \
        half8 bc[8];                                                                     \
        _Pragma("unroll") for (int ni = 0; ni < 8; ++ni)                                 \
            bc[ni] = *(const half8*)&lds[boff[ni]];                                      \
        _Pragma("unroll") for (int ks = 0; ks < 8; ++ks) {                               \
            half8 bn[8];                                                                 \
            if (ks < 7) {                                                                \
                _Pragma("unroll") for (int ni = 0; ni < 8; ++ni)                         \
                    bn[ni] = *(const half8*)&lds[(ks + 1) * 4096 + boff[ni]];            \
            }                                                                            \
            _Pragma("unroll") for (int ni = 0; ni < 8; ++ni)                             \
                acc[ni] = __builtin_amdgcn_mfma_f32_16x16x32_f16(bc[ni], SRC[ks],        \
                                                                 acc[ni], 0, 0, 0);      \
            _Pragma("unroll") for (int ni = 0; ni < 8; ++ni) bc[ni] = bn[ni];            \
        }                                                                                \
        const int row = rbase + (C) * 16 + lr;                                           \
        const float dv = dinv[min(row, M - 1)];                                          \
        if (row < M) {                                                                   \
            _Pragma("unroll") for (int ni = 0; ni < 8; ++ni) {                           \
                US4 o;                                                                   \
                o.x = f2h(acc[ni][0] * dv); o.y = f2h(acc[ni][1] * dv);                  \
                o.z = f2h(acc[ni][2] * dv); o.w = f2h(acc[ni][3] * dv);                  \
                *(US4*)(Chh + (size_t)row * 128 + ni * 16 + g * 4) = o;                  \
            }                                                                            \
        }                                                                                \
    }

    STAGE(0)
    __syncthreads();
    LOADCHUNK(0, aA)
    LOADCHUNK(1, aB)
    COMPUTE(0, aA, 0)
    COMPUTE(1, aB, 0)
    __syncthreads();   // all waves done reading half-0
    STAGE(1)
    __syncthreads();
    COMPUTE(0, aA, 1)  // A registers reused — A read ONCE from global
    COMPUTE(1, aB, 1)

#undef STAGE
#undef LOADCHUNK
#undef COMPUTE
}

// ================= aggregation: out[d] = relu(b + dinv[d]*(hs[d] + sum hs[s])) =========
__global__ __launch_bounds__(256) void k_aggregate(const unsigned short* __restrict__ hs,
                                                   const int* __restrict__ row_start,
                                                   const unsigned short* __restrict__ csr,
                                                   const float* __restrict__ dinv,
                                                   const float* __restrict__ bias,
                                                   unsigned short* __restrict__ out) {
    const int wid = blockIdx.x * 4 + (threadIdx.x >> 6);
    if (wid >= 2 * N_NODES) return;
    const int half = (wid >= N_NODES) ? 1 : 0;
    const int node = wid - half * N_NODES;
    const int lane = threadIdx.x & 63;
    const int sub = lane >> 4;
    const int fl = lane & 15;
    const unsigned int* hu = (const unsigned int*)(hs + (size_t)half * N_NODES * 128);
    const h2v e0v = {(_Float16)1.0f, (_Float16)0.0f};
    const h2v e1v = {(_Float16)0.0f, (_Float16)1.0f};

    float acc[8] = {};
    const int s0 = row_start[node], s1 = row_start[node + 1];
    const unsigned short* row = csr + s0;
    const int n = s1 - s0;

#define EDGEPAIR(VA, VB)                                                                   \
    {                                                                                      \
        h2v s;                                                                             \
        s = __builtin_bit_cast(h2v, VA.x) + __builtin_bit_cast(h2v, VB.x);                 \
        acc[0] = __builtin_amdgcn_fdot2(s, e0v, acc[0], false);                            \
        acc[1] = __builtin_amdgcn_fdot2(s, e1v, acc[1], false);                            \
        s = __builtin_bit_cast(h2v, VA.y) + __builtin_bit_cast(h2v, VB.y);                 \
        acc[2] = __builtin_amdgcn_fdot2(s, e0v, acc[2], false);                            \
        acc[3] = __builtin_amdgcn_fdot2(s, e1v, acc[3], false);                            \
        s = __builtin_bit_cast(h2v, VA.z) + __builtin_bit_cast(h2v, VB.z);                 \
        acc[4] = __builtin_amdgcn_fdot2(s, e0v, acc[4], false);                            \
        acc[5] = __builtin_amdgcn_fdot2(s, e1v, acc[5], false);                            \
        s = __builtin_bit_cast(h2v, VA.w) + __builtin_bit_cast(h2v, VB.w);                 \
        acc[6] = __builtin_amdgcn_fdot2(s, e0v, acc[6], false);                            \
        acc[7] = __builtin_amdgcn_fdot2(s, e1v, acc[7], false);                            \
    }

    const int nfull = n & ~7;
    int j = 0;
    for (; j < nfull; j += 8) {
        const int sa = row[j + sub * 2];
        const int sb = row[j + sub * 2 + 1];
        const uint4 va = *(const uint4*)(hu + (size_t)sa * 64 + fl * 4);
        const uint4 vb = *(const uint4*)(hu + (size_t)sb * 64 + fl * 4);
        EDGEPAIR(va, vb)
    }
    if (j < n) {
        const int ia = j + sub * 2, ib = ia + 1;
        uint4 va = {0, 0, 0, 0}, vb = {0, 0, 0, 0};
        if (ia < n) va = *(const uint4*)(hu + (size_t)row[ia] * 64 + fl * 4);
        if (ib < n) vb = *(const uint4*)(hu + (size_t)row[ib] * 64 + fl * 4);
        EDGEPAIR(va, vb)
    }
#undef EDGEPAIR

#pragma unroll
    for (int i = 0; i < 8; ++i) {
        acc[i] += __shfl_xor(acc[i], 16, 64);
        acc[i] += __shfl_xor(acc[i], 32, 64);
    }

    if (sub == 0) {
        const float dd = dinv[node];
        const uint4 sh = *(const uint4*)(hu + (size_t)node * 64 + fl * 4);
        const float4 b0 = *(const float4*)(bias + half * 128 + fl * 8);
        const float4 b1 = *(const float4*)(bias + half * 128 + fl * 8 + 4);
        float r[8];
        r[0] = fmaf(acc[0] + h2f((unsigned short)(sh.x & 0xffff)), dd, b0.x);
        r[1] = fmaf(acc[1] + h2f((unsigned short)(sh.x >> 16)),    dd, b0.y);
        r[2] = fmaf(acc[2] + h2f((unsigned short)(sh.y & 0xffff)), dd, b0.z);
        r[3] = fmaf(acc[3] + h2f((unsigned short)(sh.y >> 16)),    dd, b0.w);
        r[4] = fmaf(acc[4] + h2f((unsigned short)(sh.z & 0xffff)), dd, b1.x);
        r[5] = fmaf(acc[5] + h2f((unsigned short)(sh.z >> 16)),    dd, b1.y);
        r[6] = fmaf(acc[6] + h2f((unsigned short)(sh.w & 0xffff)), dd, b1.z);
        r[7] = fmaf(acc[7] + h2f((unsigned short)(sh.w >> 16)),    dd, b1.w);
#pragma unroll
        for (int i = 0; i < 8; ++i) r[i] = fmaxf(r[i], 0.f);
        uint4 o;
        o.x = (unsigned int)f2h(r[0]) | ((unsigned int)f2h(r[1]) << 16);
        o.y = (unsigned int)f2h(r[2]) | ((unsigned int)f2h(r[3]) << 16);
        o.z = (unsigned int)f2h(r[4]) | ((unsigned int)f2h(r[5]) << 16);
        o.w = (unsigned int)f2h(r[6]) | ((unsigned int)f2h(r[7]) << 16);
        *(uint4*)((unsigned int*)(out + (size_t)half * N_NODES * 128) +
                  (size_t)node * 64 + fl * 4) = o;
    }
}

// ================= pooling (batch sorted) + head =================
__global__ void k_pool(const unsigned short* __restrict__ h2, const int* __restrict__ batch,
                       float* __restrict__ pooled) {
    const int strip = blockIdx.x * 2 + (threadIdx.x >> 7);
    const int tf = threadIdx.x & 127;
    const int f = tf * 2;
    const unsigned short* base = h2 + (size_t)(f >> 7) * N_NODES * 128 + (f & 127);
    const int n0 = strip * 40, n1 = n0 + 40;
    int g = batch[n0];
    float ax = 0.f, ay = 0.f;
    for (int n = n0; n < n1; ++n) {
        const int bg = batch[n];
        if (bg != g) {
            unsafeAtomicAdd(&pooled[g * NFEAT + f], ax);
            unsafeAtomicAdd(&pooled[g * NFEAT + f + 1], ay);
            ax = ay = 0.f;
            g = bg;
        }
        const unsigned int u = *(const unsigned int*)(base + (size_t)n * 128);
        ax += h2f((unsigned short)(u & 0xffff));
        ay += h2f((unsigned short)(u >> 16));
    }
    unsafeAtomicAdd(&pooled[g * NFEAT + f], ax);
    unsafeAtomicAdd(&pooled[g * NFEAT + f + 1], ay);
}

__global__ void k_final(const float* __restrict__ pooled, const float* __restrict__ Wout,
                        const float* __restrict__ bout, float* __restrict__ out) {
    const int g = blockIdx.x, t = threadIdx.x;
    float v = pooled[g * NFEAT + t] * Wout[t];
#pragma unroll
    for (int off = 32; off > 0; off >>= 1) v += __shfl_down(v, off, 64);
    __shared__ float sred[4];
    if ((t & 63) == 0) sred[t >> 6] = v;
    __syncthreads();
    if (t == 0) out[g] = sred[0] + sred[1] + sred[2] + sred[3] + bout[0];
}

extern "C" void kernel_launch(void* const* d_in, const int* in_sizes, int n_in,
                              void* d_out, int out_size, void* d_ws, size_t ws_size,
                              hipStream_t stream) {
    const float* x     = (const float*)d_in[0];
    const int*   ei    = (const int*)d_in[1];
    const int*   batch = (const int*)d_in[2];
    const float* W1    = (const float*)d_in[3];
    const float* b1    = (const float*)d_in[4];
    const float* W2    = (const float*)d_in[5];
    const float* b2    = (const float*)d_in[6];
    const float* Wout  = (const float*)d_in[7];
    const float* bout  = (const float*)d_in[8];
    float* out = (float*)d_out;

    const int* srcp = ei;
    const int* dstp = ei + NEDGE;

    const size_t NE128 = (size_t)N_NODES * 128;
    unsigned short* hA = (unsigned short*)d_ws;            // [2][N][128] fp16 (dinv-scaled)
    unsigned short* hB = hA + 2 * NE128;                   // [2][N][128] fp16
    float* dinv      = (float*)(hB + 2 * NE128);           // 50000
    float* pooled    = dinv + N_NODES;                     // 16384
    int*   row_start = (int*)(pooled + NGRAPH * NFEAT);    // 50001 (+pad)
    int*   bcnt      = row_start + N_NODES + 3;            // 98
    unsigned short* csr = (unsigned short*)(bcnt + NBUCK + 2);  // 800000 ushort
    unsigned int* tmp = (unsigned int*)(csr + NEDGE);      // 98*16384 uint
    unsigned short* w1t = (unsigned short*)(tmp + (size_t)NBUCK * BWIN);  // 65536 each
    unsigned short* w2t = w1t + 65536;

    // ---- prep (also zeroes bcnt + pooled) ----
    k_prep_w<<<512, 256, 0, stream>>>(W1, W2, w1t, w2t, bcnt, pooled);

    // ---- CSR build: bucketed two-phase (prefix folded into k_build) ----
    k_bin<<<(NEDGE + 1023) / 1024, 256, 0, stream>>>(srcp, dstp, bcnt, tmp);
    k_build<<<NBUCK, 256, 0, stream>>>(tmp, bcnt, row_start, dinv, csr);

    const int ggrid = 391;                       // 391 x 128 rows, both halves per block
    const int agg_grid = (2 * N_NODES + 3) / 4;  // 25000

    // ---- layer 1 (x f32 -> fp16 + dinv-scale fused into GEMM) ----
    k_gemm_mfma<true><<<ggrid, 256, 0, stream>>>(x, nullptr, w1t, dinv, hA, N_NODES);
    k_aggregate<<<agg_grid, 256, 0, stream>>>(hA, row_start, csr, dinv, b1, hB);

    // ---- layer 2 ----
    k_gemm_mfma<false><<<ggrid, 256, 0, stream>>>(nullptr, hB, w2t, dinv, hA, N_NODES);
    k_aggregate<<<agg_grid, 256, 0, stream>>>(hA, row_start, csr, dinv, b2, hB);

    // ---- pooling + head ----
    k_pool<<<625, 256, 0, stream>>>(hB, batch, pooled);
    k_final<<<NGRAPH, 256, 0, stream>>>(pooled, Wout, bout, out);
}